// Round 1
// baseline (18735.863 us; speedup 1.0000x reference)
//
#include <hip/hip_runtime.h>
#include <hip/hip_bf16.h>

typedef __bf16 bf16_t;
typedef __attribute__((ext_vector_type(8))) __bf16 bf16x8;
typedef __attribute__((ext_vector_type(4))) float f32x4;

#define MFMA16(a, b, c) __builtin_amdgcn_mfma_f32_16x16x32_bf16((a), (b), (c), 0, 0, 0)

namespace {
constexpr int TSEQ = 512, DDIM = 512, NB = 64;
// ws byte offsets
constexpr size_t OFF_ENC_HBUF = 0;        // bf16 [2 layer][2 par][64][512]
constexpr size_t OFF_DEC_HBUF = 262144;   // bf16 [2][2][64][512]
constexpr size_t OFF_DEC_YBUF = 524288;   // bf16 [2 par][64][512]
constexpr size_t OFF_HT       = 655360;   // f32 [2][64][512]
constexpr size_t OFF_CT       = 917504;
constexpr size_t OFF_H2       = 1179648;
constexpr size_t OFF_C2       = 1441792;
constexpr size_t OFF_FLAGS_E  = 1703936;  // int [4 grp][64 wg][16]
constexpr size_t OFF_FLAGS_D  = 1720320;
constexpr size_t FLAGS_BYTES  = 16384;

template <int V> struct IC { static constexpr int v = V; };
}  // namespace

__device__ __forceinline__ float sigm_f(float x) { return 1.f / (1.f + __expf(-x)); }
__device__ __forceinline__ float tanh_f(float x) {
  x = fminf(15.f, fmaxf(-15.f, x));
  const float e = __expf(-2.f * x);
  return (1.f - e) / (1.f + e);
}
__device__ __forceinline__ bf16x8 cvt8(const float* __restrict__ p) {
  const float4 a = *(const float4*)p;
  const float4 b = *(const float4*)(p + 4);
  bf16x8 r;
  r[0] = (bf16_t)a.x; r[1] = (bf16_t)a.y; r[2] = (bf16_t)a.z; r[3] = (bf16_t)a.w;
  r[4] = (bf16_t)b.x; r[5] = (bf16_t)b.y; r[6] = (bf16_t)b.z; r[7] = (bf16_t)b.w;
  return r;
}

// MODE 0 = encoder (x from global fp32, writes hT/cT at t=511)
// MODE 1 = decoder (x from y ring buffer, writes out; init from h2/c2/initial)
template <int MODE>
__global__ __launch_bounds__(256, 2) void lstm_pass(
    const float* __restrict__ x, const float* __restrict__ initial,
    const float* __restrict__ Wih, const float* __restrict__ Whh,
    const float* __restrict__ bih, const float* __restrict__ bhh,
    const float* __restrict__ h_init, const float* __restrict__ c_init,
    bf16_t* __restrict__ hbuf, bf16_t* __restrict__ ybuf,
    float* __restrict__ hT, float* __restrict__ cT,
    float* __restrict__ out, int* __restrict__ flags) {
  const int wg = blockIdx.x;
  const int grp = wg >> 6;   // batch group (16 rows each)
  const int slc = wg & 63;   // h-slice (8 cols each)
  const int tid = threadIdx.x;
  const int wave = tid >> 6; // K-quarter: 0,1 = input half; 2,3 = recurrent half
  const int lane = tid & 63;
  const int b0 = grp << 4;
  const int d0 = slc << 3;
  int* gfl = flags + grp * (64 * 16);

  __shared__ float gbuf[4][16][33];
  __shared__ float cst[2][16][8];
  __shared__ float bias_l[2][32];

  const int c15 = lane & 15;
  const int kg = lane >> 4;

  // ---- persistent weights in registers: B-fragments, gate-permuted ----
  // local col n in [0,32): gate = n>>3 (i,f,g,o), elem = n&7 -> global row gate*512 + d0 + elem
  bf16x8 wA[2][8], wB[2][8];  // [layer][kstep]; wA = local cols 0..15, wB = 16..31
  {
    const float* Wsrc = (wave < 2) ? Wih : Whh;
    const int kb = (wave & 1) << 8;
#pragma unroll
    for (int l = 0; l < 2; ++l)
#pragma unroll
      for (int nt = 0; nt < 2; ++nt)
#pragma unroll
        for (int ks = 0; ks < 8; ++ks) {
          const int n = nt * 16 + c15;
          const int grow = (n >> 3) * DDIM + d0 + (n & 7);
          const float* p = Wsrc + (size_t)(l * 2048 + grow) * DDIM + kb + ks * 32 + kg * 8;
          if (nt == 0) wA[l][ks] = cvt8(p);
          else         wB[l][ks] = cvt8(p);
        }
  }
  if (tid < 64) {
    const int l = tid >> 5, n = tid & 31;
    const int grow = (n >> 3) * DDIM + d0 + (n & 7);
    bias_l[l][n] = bih[l * 2048 + grow] + bhh[l * 2048 + grow];
  }
  {  // c-state + parity-1 h-buffer init
    const int l = tid >> 7;
    const int rw = (tid >> 3) & 15;
    const int d = tid & 7;
    const int b = b0 + rw, dc = d0 + d;
    if (MODE == 0) {
      cst[l][rw][d] = 0.f;
      hbuf[((l * 2 + 1) * NB + b) * DDIM + dc] = (bf16_t)0.f;
    } else {
      cst[l][rw][d] = c_init[(l * NB + b) * DDIM + dc];
      hbuf[((l * 2 + 1) * NB + b) * DDIM + dc] = (bf16_t)h_init[(l * NB + b) * DDIM + dc];
      if (l == 0) ybuf[(1 * NB + b) * DDIM + dc] = (bf16_t)initial[dc];
    }
  }
  __syncthreads();
  if (tid == 0)
    __hip_atomic_store(&gfl[slc * 16], 1, __ATOMIC_RELEASE, __HIP_MEMORY_SCOPE_AGENT);

  auto level = [&](auto lcc, int t, int p, int rp, int wv, int sg) {
    constexpr int LC = decltype(lcc)::v;
    // ---- wait: all 64 WGs of this batch group at >= wv ----
    if (tid < 64) {
      while (__hip_atomic_load(&gfl[tid * 16], __ATOMIC_RELAXED, __HIP_MEMORY_SCOPE_AGENT) < wv) {}
      __builtin_amdgcn_fence(__ATOMIC_ACQUIRE, "agent");
    }
    __syncthreads();

    f32x4 acc0 = {0.f, 0.f, 0.f, 0.f};
    f32x4 acc1 = {0.f, 0.f, 0.f, 0.f};
    const int b = b0 + c15;
    if (wave < 2) {
      const int kq = wave << 8;
      if (MODE == 0 && LC == 0) {
        const float* ap = x + ((size_t)b * TSEQ + t) * DDIM + kq + kg * 8;
#pragma unroll
        for (int ks = 0; ks < 8; ++ks) {
          const bf16x8 a = cvt8(ap + ks * 32);
          acc0 = MFMA16(a, wA[LC][ks], acc0);
          acc1 = MFMA16(a, wB[LC][ks], acc1);
        }
      } else {
        const bf16_t* src = (LC == 1) ? (hbuf + (size_t)(0 * 2 + p) * NB * DDIM)
                                      : (ybuf + (size_t)rp * NB * DDIM);
        const bf16_t* ap = src + b * DDIM + kq + kg * 8;
#pragma unroll
        for (int ks = 0; ks < 8; ++ks) {
          const bf16x8 a = *(const bf16x8*)(ap + ks * 32);
          acc0 = MFMA16(a, wA[LC][ks], acc0);
          acc1 = MFMA16(a, wB[LC][ks], acc1);
        }
      }
    } else {
      const int kq = (wave - 2) << 8;
      const bf16_t* ap = hbuf + (size_t)(LC * 2 + rp) * NB * DDIM + b * DDIM + kq + kg * 8;
#pragma unroll
      for (int ks = 0; ks < 8; ++ks) {
        const bf16x8 a = *(const bf16x8*)(ap + ks * 32);
        acc0 = MFMA16(a, wA[LC][ks], acc0);
        acc1 = MFMA16(a, wB[LC][ks], acc1);
      }
    }
#pragma unroll
    for (int r = 0; r < 4; ++r) {
      gbuf[wave][kg * 4 + r][c15] = acc0[r];
      gbuf[wave][kg * 4 + r][16 + c15] = acc1[r];
    }
    __syncthreads();
    if (tid < 128) {
      const int rw = tid >> 3, d = tid & 7;
      float gi = bias_l[LC][d], gf = bias_l[LC][8 + d];
      float gg = bias_l[LC][16 + d], go = bias_l[LC][24 + d];
#pragma unroll
      for (int q = 0; q < 4; ++q) {
        gi += gbuf[q][rw][d];
        gf += gbuf[q][rw][8 + d];
        gg += gbuf[q][rw][16 + d];
        go += gbuf[q][rw][24 + d];
      }
      const float iv = sigm_f(gi), fv = sigm_f(gf), gv = tanh_f(gg), ov = sigm_f(go);
      const float cv = fv * cst[LC][rw][d] + iv * gv;
      cst[LC][rw][d] = cv;
      const float hv = ov * tanh_f(cv);
      const int b2 = b0 + rw, dc = d0 + d;
      hbuf[((LC * 2 + p) * NB + b2) * DDIM + dc] = (bf16_t)hv;
      if (MODE == 1 && LC == 1) {
        ybuf[(p * NB + b2) * DDIM + dc] = (bf16_t)hv;
        out[((size_t)b2 * TSEQ + t) * DDIM + dc] = hv;
      }
      if (MODE == 0 && t == TSEQ - 1) {
        hT[(LC * NB + b2) * DDIM + dc] = hv;
        cT[(LC * NB + b2) * DDIM + dc] = cv;
      }
    }
    __syncthreads();
    if (tid == 0)
      __hip_atomic_store(&gfl[slc * 16], sg, __ATOMIC_RELEASE, __HIP_MEMORY_SCOPE_AGENT);
  };

  for (int t = 0; t < TSEQ; ++t) {
    const int p = t & 1, rp = p ^ 1;
    level(IC<0>{}, t, p, rp, 2 * t + 1, 2 * t + 2);
    level(IC<1>{}, t, p, rp, 2 * t + 2, 2 * t + 3);
  }
}

__global__ __launch_bounds__(512) void vae_kernel(
    const float* __restrict__ hT, const float* __restrict__ cT,
    const float* __restrict__ hmuW, const float* __restrict__ hmub,
    const float* __restrict__ hsigW, const float* __restrict__ hsigb,
    const float* __restrict__ houtW, const float* __restrict__ houtb,
    const float* __restrict__ cmuW, const float* __restrict__ cmub,
    const float* __restrict__ csigW, const float* __restrict__ csigb,
    const float* __restrict__ coutW, const float* __restrict__ coutb,
    const float* __restrict__ eps_h, const float* __restrict__ eps_c,
    float* __restrict__ h2, float* __restrict__ c2, float* __restrict__ out) {
  const int bid = blockIdx.x;  // 0..255 = (hc, layer, b)
  const int b = bid & 63;
  const int l = (bid >> 6) & 1;
  const int hc = bid >> 7;
  const int tid = threadIdx.x;

  const float* S    = (hc ? cT : hT) + (l * 64 + b) * 512;
  const float* muW  = (hc ? cmuW : hmuW) + l * 64 * 512;
  const float* mub  = (hc ? cmub : hmub) + l * 64;
  const float* sigW = (hc ? csigW : hsigW) + l * 64 * 512;
  const float* sigb = (hc ? csigb : hsigb) + l * 64;
  const float* outW = (hc ? coutW : houtW) + l * 512 * 64;
  const float* outb = (hc ? coutb : houtb) + l * 512;
  const float* eps  = (hc ? eps_c : eps_h) + (l * 64 + b) * 64;
  float* S2 = (hc ? c2 : h2) + (l * 64 + b) * 512;

  __shared__ float srow[512];
  __shared__ float z[64];
  srow[tid] = S[tid];
  __syncthreads();
  if (tid < 64) {
    const float* wm = muW + tid * 512;
    const float* ws = sigW + tid * 512;
    float mu = mub[tid], sg = sigb[tid];
    for (int d = 0; d < 512; ++d) {
      mu = fmaf(srow[d], wm[d], mu);
      sg = fmaf(srow[d], ws[d], sg);
    }
    z[tid] = mu + eps[tid] * sg;
    const size_t base = (size_t)64 * 512 * 512;
    const size_t idx = ((size_t)(hc * 2 + l) * 64 + b) * 64 + tid;
    out[base + idx] = mu;
    out[base + 4 * 64 * 64 + idx] = sg;
  }
  __syncthreads();
  {
    const float* wo = outW + tid * 64;
    float acc = outb[tid];
#pragma unroll 8
    for (int g = 0; g < 64; ++g) acc = fmaf(z[g], wo[g], acc);
    S2[tid] = acc;
  }
}

extern "C" void kernel_launch(void* const* d_in, const int* in_sizes, int n_in,
                              void* d_out, int out_size, void* d_ws, size_t ws_size,
                              hipStream_t stream) {
  const float* x        = (const float*)d_in[0];
  const float* initial  = (const float*)d_in[1];
  const float* eWih     = (const float*)d_in[2];
  const float* eWhh     = (const float*)d_in[3];
  const float* ebih     = (const float*)d_in[4];
  const float* ebhh     = (const float*)d_in[5];
  const float* dWih     = (const float*)d_in[6];
  const float* dWhh     = (const float*)d_in[7];
  const float* dbih     = (const float*)d_in[8];
  const float* dbhh     = (const float*)d_in[9];
  const float* hmuW     = (const float*)d_in[10];
  const float* hmub     = (const float*)d_in[11];
  const float* hsigW    = (const float*)d_in[12];
  const float* hsigb    = (const float*)d_in[13];
  const float* houtW    = (const float*)d_in[14];
  const float* houtb    = (const float*)d_in[15];
  const float* cmuW     = (const float*)d_in[16];
  const float* cmub     = (const float*)d_in[17];
  const float* csigW    = (const float*)d_in[18];
  const float* csigb    = (const float*)d_in[19];
  const float* coutW    = (const float*)d_in[20];
  const float* coutb    = (const float*)d_in[21];
  const float* eps_h    = (const float*)d_in[22];
  const float* eps_c    = (const float*)d_in[23];

  char* ws = (char*)d_ws;
  bf16_t* enc_hbuf = (bf16_t*)(ws + OFF_ENC_HBUF);
  bf16_t* dec_hbuf = (bf16_t*)(ws + OFF_DEC_HBUF);
  bf16_t* dec_ybuf = (bf16_t*)(ws + OFF_DEC_YBUF);
  float* hT = (float*)(ws + OFF_HT);
  float* cT = (float*)(ws + OFF_CT);
  float* h2 = (float*)(ws + OFF_H2);
  float* c2 = (float*)(ws + OFF_C2);
  int* fe = (int*)(ws + OFF_FLAGS_E);
  int* fd = (int*)(ws + OFF_FLAGS_D);
  float* out = (float*)d_out;

  hipMemsetAsync(ws + OFF_FLAGS_E, 0, 2 * FLAGS_BYTES, stream);

  lstm_pass<0><<<256, 256, 0, stream>>>(x, nullptr, eWih, eWhh, ebih, ebhh,
                                        nullptr, nullptr, enc_hbuf, nullptr,
                                        hT, cT, nullptr, fe);
  vae_kernel<<<256, 512, 0, stream>>>(hT, cT, hmuW, hmub, hsigW, hsigb, houtW, houtb,
                                      cmuW, cmub, csigW, csigb, coutW, coutb,
                                      eps_h, eps_c, h2, c2, out);
  lstm_pass<1><<<256, 256, 0, stream>>>(nullptr, initial, dWih, dWhh, dbih, dbhh,
                                        h2, c2, dec_hbuf, dec_ybuf,
                                        nullptr, nullptr, out, fd);
}

// Round 2
// 7738.581 us; speedup vs baseline: 2.4211x; 2.4211x over previous
//
#include <hip/hip_runtime.h>
#include <hip/hip_bf16.h>

typedef __bf16 bf16_t;
typedef __attribute__((ext_vector_type(8))) __bf16 bf16x8;
typedef __attribute__((ext_vector_type(4))) float f32x4;
typedef __attribute__((ext_vector_type(4))) int i32x4;

#define MFMA16(a, b, c) __builtin_amdgcn_mfma_f32_16x16x32_bf16((a), (b), (c), 0, 0, 0)

namespace {
constexpr int TSEQ = 512, DDIM = 512, NB = 64;
constexpr size_t OFF_ENC_HBUF = 0;        // bf16 [2 layer][2 slot][64][512]
constexpr size_t OFF_DEC_HBUF = 262144;   // bf16 [2][2][64][512]
constexpr size_t OFF_DEC_YBUF = 524288;   // bf16 [2 slot][64][512]
constexpr size_t OFF_HT       = 655360;   // f32 [2][64][512]
constexpr size_t OFF_CT       = 917504;
constexpr size_t OFF_H2       = 1179648;
constexpr size_t OFF_C2       = 1441792;
constexpr size_t OFF_FLAGS_E  = 1703936;  // int [4 grp][64] packed
constexpr size_t OFF_FLAGS_D  = 1720320;
constexpr size_t FLAGS_BYTES  = 16384;
template <int V> struct IC { static constexpr int v = V; };
}  // namespace

__device__ __forceinline__ float sigm_f(float x) { return 1.f / (1.f + __expf(-x)); }
__device__ __forceinline__ float tanh_f(float x) {
  x = fminf(15.f, fmaxf(-15.f, x));
  const float e = __expf(-2.f * x);
  return (1.f - e) / (1.f + e);
}
__device__ __forceinline__ bf16x8 cvt8(const float* __restrict__ p) {
  const float4 a = *(const float4*)p;
  const float4 b = *(const float4*)(p + 4);
  bf16x8 r;
  r[0] = (bf16_t)a.x; r[1] = (bf16_t)a.y; r[2] = (bf16_t)a.z; r[3] = (bf16_t)a.w;
  r[4] = (bf16_t)b.x; r[5] = (bf16_t)b.y; r[6] = (bf16_t)b.z; r[7] = (bf16_t)b.w;
  return r;
}

union FRAG { i32x4 i; bf16x8 v; };

// L1+L2-bypassing 16B load (data goes through L3, the cross-XCD coherence point)
__device__ __forceinline__ void ldg_issue(const bf16_t* p, i32x4& d) {
  asm volatile("global_load_dwordx4 %0, %1, off sc0 sc1" : "=v"(d) : "v"(p) : "memory");
}
__device__ __forceinline__ void vm_wait0() {
  asm volatile("s_waitcnt vmcnt(0)" ::: "memory");
  __builtin_amdgcn_sched_barrier(0);  // rule #18: keep MFMAs below the wait
}
// packed bf16 pair store, agent scope (write-through to L3)
__device__ __forceinline__ void stg_pair(bf16_t* p, float a, float b) {
  union { bf16_t h[2]; unsigned u; } x;
  x.h[0] = (bf16_t)a; x.h[1] = (bf16_t)b;
  __hip_atomic_store((unsigned*)p, x.u, __ATOMIC_RELAXED, __HIP_MEMORY_SCOPE_AGENT);
}
__device__ __forceinline__ void poll_ge(int* f, int wv) {
  int v;
  do { v = __hip_atomic_load(f, __ATOMIC_RELAXED, __HIP_MEMORY_SCOPE_AGENT); }
  while (__any(v < wv));
}
__device__ __forceinline__ void post_flag(int* f, int v) {
  __hip_atomic_store(f, v, __ATOMIC_RELAXED, __HIP_MEMORY_SCOPE_AGENT);
}

__device__ __forceinline__ void load_weights(const float* Wih, const float* Whh,
                                             int wave, int c15, int kg, int d0,
                                             bf16x8 (&wA)[2][8], bf16x8 (&wB)[2][8]) {
  const float* Wsrc = (wave < 2) ? Wih : Whh;
  const int kb = (wave & 1) << 8;
#pragma unroll
  for (int l = 0; l < 2; ++l)
#pragma unroll
    for (int nt = 0; nt < 2; ++nt)
#pragma unroll
      for (int ks = 0; ks < 8; ++ks) {
        const int n = nt * 16 + c15;
        const int grow = (n >> 3) * DDIM + d0 + (n & 7);
        const float* p = Wsrc + (size_t)(l * 2048 + grow) * DDIM + kb + ks * 32 + kg * 8;
        if (nt == 0) wA[l][ks] = cvt8(p);
        else         wB[l][ks] = cvt8(p);
      }
}

// ---------------- encoder: diagonal wavefront, 513 super-levels ----------------
__global__ __launch_bounds__(256, 1) void enc_pass(
    const float* __restrict__ x,
    const float* __restrict__ Wih, const float* __restrict__ Whh,
    const float* __restrict__ bih, const float* __restrict__ bhh,
    bf16_t* __restrict__ hbuf, float* __restrict__ hT, float* __restrict__ cT,
    int* __restrict__ flags) {
  const int wg = blockIdx.x;
  const int grp = wg >> 6, slc = wg & 63;
  const int tid = threadIdx.x;
  const int wave = tid >> 6, lane = tid & 63;
  const int b0 = grp << 4, d0 = slc << 3;
  int* gfl = flags + grp * 64;

  __shared__ float gbuf[2][4][16][33];
  __shared__ float cst[2][16][8];
  __shared__ float bias_l[2][32];

  const int c15 = lane & 15, kg = lane >> 4;
  const int b = b0 + c15;

  bf16x8 wA[2][8], wB[2][8];
  load_weights(Wih, Whh, wave, c15, kg, d0, wA, wB);
  if (tid < 64) {
    const int l = tid >> 5, n = tid & 31;
    const int grow = (n >> 3) * DDIM + d0 + (n & 7);
    bias_l[l][n] = bih[l * 2048 + grow] + bhh[l * 2048 + grow];
  }
  if (tid < 128) {  // cst=0; h0 slot1 = 0; h1 slot0 = 0
    const int l = tid >> 6, r6 = tid & 63, rw = r6 >> 2, dp = r6 & 3;
    cst[l][rw][2 * dp] = 0.f; cst[l][rw][2 * dp + 1] = 0.f;
    const int slot = (l == 0) ? 1 : 0;
    stg_pair(&hbuf[((size_t)(l * 2 + slot) * NB + b0 + rw) * DDIM + d0 + 2 * dp], 0.f, 0.f);
  }
  __syncthreads();
  if (tid == 0) post_flag(&gfl[slc], 1);

  for (int s = 0; s <= TSEQ; ++s) {
    const int p = s & 1, rp = p ^ 1;
    // -- pre-barrier: L0 x-half (external data) overlapped with poll --
    if (s < TSEQ && wave < 2) {
      f32x4 a0 = {0.f, 0.f, 0.f, 0.f}, a1 = {0.f, 0.f, 0.f, 0.f};
      const int kq = wave << 8;
      const float* ap = x + ((size_t)b * TSEQ + s) * DDIM + kq + kg * 8;
#pragma unroll
      for (int ks = 0; ks < 8; ++ks) {
        const bf16x8 a = cvt8(ap + ks * 32);
        a0 = MFMA16(a, wA[0][ks], a0);
        a1 = MFMA16(a, wB[0][ks], a1);
      }
#pragma unroll
      for (int r = 0; r < 4; ++r) {
        gbuf[0][wave][kg * 4 + r][c15] = a0[r];
        gbuf[0][wave][kg * 4 + r][16 + c15] = a1[r];
      }
    }
    if (wave == 2) poll_ge(&gfl[lane], s + 1);
    __syncthreads();
    // -- fresh halves --
    if (wave >= 2) {
      const int kq = (wave - 2) << 8;
      FRAG f0[8], f1[8];
      const bf16_t* a0p = hbuf + ((size_t)(0 * 2 + rp) * NB + b) * DDIM + kq + kg * 8;
      const bf16_t* a1p = hbuf + ((size_t)(1 * 2 + rp) * NB + b) * DDIM + kq + kg * 8;
      if (s < TSEQ) {
#pragma unroll
        for (int ks = 0; ks < 8; ++ks) ldg_issue(a0p + ks * 32, f0[ks].i);
      }
      if (s >= 1) {
#pragma unroll
        for (int ks = 0; ks < 8; ++ks) ldg_issue(a1p + ks * 32, f1[ks].i);
      }
      vm_wait0();
      if (s < TSEQ) {
        f32x4 a0 = {0.f, 0.f, 0.f, 0.f}, a1 = {0.f, 0.f, 0.f, 0.f};
#pragma unroll
        for (int ks = 0; ks < 8; ++ks) {
          a0 = MFMA16(f0[ks].v, wA[0][ks], a0);
          a1 = MFMA16(f0[ks].v, wB[0][ks], a1);
        }
#pragma unroll
        for (int r = 0; r < 4; ++r) {
          gbuf[0][wave][kg * 4 + r][c15] = a0[r];
          gbuf[0][wave][kg * 4 + r][16 + c15] = a1[r];
        }
      }
      if (s >= 1) {
        f32x4 a0 = {0.f, 0.f, 0.f, 0.f}, a1 = {0.f, 0.f, 0.f, 0.f};
#pragma unroll
        for (int ks = 0; ks < 8; ++ks) {
          a0 = MFMA16(f1[ks].v, wA[1][ks], a0);
          a1 = MFMA16(f1[ks].v, wB[1][ks], a1);
        }
#pragma unroll
        for (int r = 0; r < 4; ++r) {
          gbuf[1][wave][kg * 4 + r][c15] = a0[r];
          gbuf[1][wave][kg * 4 + r][16 + c15] = a1[r];
        }
      }
    } else if (s >= 1) {  // waves 0,1: L1 input half = h0(s-1)
      const int kq = wave << 8;
      FRAG f[8];
      const bf16_t* ap = hbuf + ((size_t)(0 * 2 + rp) * NB + b) * DDIM + kq + kg * 8;
#pragma unroll
      for (int ks = 0; ks < 8; ++ks) ldg_issue(ap + ks * 32, f[ks].i);
      vm_wait0();
      f32x4 a0 = {0.f, 0.f, 0.f, 0.f}, a1 = {0.f, 0.f, 0.f, 0.f};
#pragma unroll
      for (int ks = 0; ks < 8; ++ks) {
        a0 = MFMA16(f[ks].v, wA[1][ks], a0);
        a1 = MFMA16(f[ks].v, wB[1][ks], a1);
      }
#pragma unroll
      for (int r = 0; r < 4; ++r) {
        gbuf[1][wave][kg * 4 + r][c15] = a0[r];
        gbuf[1][wave][kg * 4 + r][16 + c15] = a1[r];
      }
    }
    __syncthreads();
    // -- epilogue: both layers --
    if (tid < 128) {
      const int ll = tid >> 6, r6 = tid & 63, rw = r6 >> 2, dp = r6 & 3;
      const bool act = (ll == 0) ? (s < TSEQ) : (s >= 1);
      if (act) {
        float hv2[2], cv2[2];
#pragma unroll
        for (int e2 = 0; e2 < 2; ++e2) {
          const int e = dp * 2 + e2;
          float gi = bias_l[ll][e],      gf = bias_l[ll][8 + e];
          float gg = bias_l[ll][16 + e], go = bias_l[ll][24 + e];
#pragma unroll
          for (int q = 0; q < 4; ++q) {
            gi += gbuf[ll][q][rw][e];
            gf += gbuf[ll][q][rw][8 + e];
            gg += gbuf[ll][q][rw][16 + e];
            go += gbuf[ll][q][rw][24 + e];
          }
          const float iv = sigm_f(gi), fv = sigm_f(gf), gv = tanh_f(gg), ov = sigm_f(go);
          const float cv = fv * cst[ll][rw][e] + iv * gv;
          cst[ll][rw][e] = cv;
          cv2[e2] = cv;
          hv2[e2] = ov * tanh_f(cv);
        }
        const int b2 = b0 + rw, dc = d0 + dp * 2;
        stg_pair(&hbuf[((size_t)(ll * 2 + p) * NB + b2) * DDIM + dc], hv2[0], hv2[1]);
        if ((ll == 0 && s == TSEQ - 1) || (ll == 1 && s == TSEQ)) {
          *(float2*)&hT[((size_t)ll * NB + b2) * DDIM + dc] = float2{hv2[0], hv2[1]};
          *(float2*)&cT[((size_t)ll * NB + b2) * DDIM + dc] = float2{cv2[0], cv2[1]};
        }
      }
    }
    vm_wait0();
    __syncthreads();
    if (tid == 0) post_flag(&gfl[slc], s + 2);
  }
}

// ---------------- decoder: serial chain, 1024 levels ----------------
__global__ __launch_bounds__(256, 1) void dec_pass(
    const float* __restrict__ initial,
    const float* __restrict__ Wih, const float* __restrict__ Whh,
    const float* __restrict__ bih, const float* __restrict__ bhh,
    const float* __restrict__ h_init, const float* __restrict__ c_init,
    bf16_t* __restrict__ hbuf, bf16_t* __restrict__ ybuf,
    float* __restrict__ out, int* __restrict__ flags) {
  const int wg = blockIdx.x;
  const int grp = wg >> 6, slc = wg & 63;
  const int tid = threadIdx.x;
  const int wave = tid >> 6, lane = tid & 63;
  const int b0 = grp << 4, d0 = slc << 3;
  int* gfl = flags + grp * 64;

  __shared__ float gbuf[4][16][33];
  __shared__ float cst[2][16][8];
  __shared__ float bias_l[2][32];

  const int c15 = lane & 15, kg = lane >> 4;
  const int b = b0 + c15;

  bf16x8 wA[2][8], wB[2][8];
  load_weights(Wih, Whh, wave, c15, kg, d0, wA, wB);
  if (tid < 64) {
    const int l = tid >> 5, n = tid & 31;
    const int grow = (n >> 3) * DDIM + d0 + (n & 7);
    bias_l[l][n] = bih[l * 2048 + grow] + bhh[l * 2048 + grow];
  }
  if (tid < 128) {  // cst from c_init; h(-1) = h_init into slot 1
    const int l = tid >> 6, r6 = tid & 63, rw = r6 >> 2, dp = r6 & 3;
    const int b2 = b0 + rw, dc = d0 + 2 * dp;
    const float2 cv = *(const float2*)&c_init[((size_t)l * NB + b2) * DDIM + dc];
    cst[l][rw][2 * dp] = cv.x; cst[l][rw][2 * dp + 1] = cv.y;
    const float2 hv = *(const float2*)&h_init[((size_t)l * NB + b2) * DDIM + dc];
    stg_pair(&hbuf[((size_t)(l * 2 + 1) * NB + b2) * DDIM + dc], hv.x, hv.y);
  }
  if (tid < 64) {  // y(-1) = initial into ybuf slot 1
    const int rw = tid >> 2, dp = tid & 3;
    const int dc = d0 + 2 * dp;
    stg_pair(&ybuf[((size_t)1 * NB + b0 + rw) * DDIM + dc], initial[dc], initial[dc + 1]);
  }
  __syncthreads();
  if (tid == 0) post_flag(&gfl[slc], 1);

  // wait for every WG's init before touching other slices
  if (wave == 0) poll_ge(&gfl[lane], 1);
  __syncthreads();

  auto level = [&](auto lcc, int t, int p, int rp) {
    constexpr int LC = decltype(lcc)::v;
    const int lvl = 2 * t + LC;
    // -- pre-barrier: recurrent half (operands >= 2 levels old) --
    if (wave >= 2) {
      const int kq = (wave - 2) << 8;
      FRAG f[8];
      const bf16_t* ap = hbuf + ((size_t)(LC * 2 + rp) * NB + b) * DDIM + kq + kg * 8;
#pragma unroll
      for (int ks = 0; ks < 8; ++ks) ldg_issue(ap + ks * 32, f[ks].i);
      vm_wait0();
      f32x4 a0 = {0.f, 0.f, 0.f, 0.f}, a1 = {0.f, 0.f, 0.f, 0.f};
#pragma unroll
      for (int ks = 0; ks < 8; ++ks) {
        a0 = MFMA16(f[ks].v, wA[LC][ks], a0);
        a1 = MFMA16(f[ks].v, wB[LC][ks], a1);
      }
#pragma unroll
      for (int r = 0; r < 4; ++r) {
        gbuf[wave][kg * 4 + r][c15] = a0[r];
        gbuf[wave][kg * 4 + r][16 + c15] = a1[r];
      }
    } else if (wave == 0) {
      poll_ge(&gfl[lane], lvl + 1);
    }
    __syncthreads();
    // -- fresh half: L0 reads y(t-1), L1 reads h0(t) --
    if (wave < 2) {
      const int kq = wave << 8;
      const bf16_t* base = (LC == 0) ? (ybuf + (size_t)rp * NB * DDIM)
                                     : (hbuf + (size_t)(0 * 2 + p) * NB * DDIM);
      FRAG f[8];
      const bf16_t* ap = base + (size_t)b * DDIM + kq + kg * 8;
#pragma unroll
      for (int ks = 0; ks < 8; ++ks) ldg_issue(ap + ks * 32, f[ks].i);
      vm_wait0();
      f32x4 a0 = {0.f, 0.f, 0.f, 0.f}, a1 = {0.f, 0.f, 0.f, 0.f};
#pragma unroll
      for (int ks = 0; ks < 8; ++ks) {
        a0 = MFMA16(f[ks].v, wA[LC][ks], a0);
        a1 = MFMA16(f[ks].v, wB[LC][ks], a1);
      }
#pragma unroll
      for (int r = 0; r < 4; ++r) {
        gbuf[wave][kg * 4 + r][c15] = a0[r];
        gbuf[wave][kg * 4 + r][16 + c15] = a1[r];
      }
    }
    __syncthreads();
    // -- epilogue --
    if (tid < 64) {
      const int rw = tid >> 2, dp = tid & 3;
      float hv2[2];
#pragma unroll
      for (int e2 = 0; e2 < 2; ++e2) {
        const int e = dp * 2 + e2;
        float gi = bias_l[LC][e],      gf = bias_l[LC][8 + e];
        float gg = bias_l[LC][16 + e], go = bias_l[LC][24 + e];
#pragma unroll
        for (int q = 0; q < 4; ++q) {
          gi += gbuf[q][rw][e];
          gf += gbuf[q][rw][8 + e];
          gg += gbuf[q][rw][16 + e];
          go += gbuf[q][rw][24 + e];
        }
        const float iv = sigm_f(gi), fv = sigm_f(gf), gv = tanh_f(gg), ov = sigm_f(go);
        const float cv = fv * cst[LC][rw][e] + iv * gv;
        cst[LC][rw][e] = cv;
        hv2[e2] = ov * tanh_f(cv);
      }
      const int b2 = b0 + rw, dc = d0 + dp * 2;
      stg_pair(&hbuf[((size_t)(LC * 2 + p) * NB + b2) * DDIM + dc], hv2[0], hv2[1]);
      if (LC == 1) {
        stg_pair(&ybuf[((size_t)p * NB + b2) * DDIM + dc], hv2[0], hv2[1]);
        *(float2*)&out[((size_t)b2 * TSEQ + t) * DDIM + dc] = float2{hv2[0], hv2[1]};
      }
    }
    vm_wait0();
    __syncthreads();
    if (tid == 0) post_flag(&gfl[slc], lvl + 2);
  };

  for (int t = 0; t < TSEQ; ++t) {
    const int p = t & 1, rp = p ^ 1;
    level(IC<0>{}, t, p, rp);
    level(IC<1>{}, t, p, rp);
  }
}

__global__ __launch_bounds__(512) void vae_kernel(
    const float* __restrict__ hT, const float* __restrict__ cT,
    const float* __restrict__ hmuW, const float* __restrict__ hmub,
    const float* __restrict__ hsigW, const float* __restrict__ hsigb,
    const float* __restrict__ houtW, const float* __restrict__ houtb,
    const float* __restrict__ cmuW, const float* __restrict__ cmub,
    const float* __restrict__ csigW, const float* __restrict__ csigb,
    const float* __restrict__ coutW, const float* __restrict__ coutb,
    const float* __restrict__ eps_h, const float* __restrict__ eps_c,
    float* __restrict__ h2, float* __restrict__ c2, float* __restrict__ out) {
  const int bid = blockIdx.x;  // (hc, layer, b)
  const int b = bid & 63;
  const int l = (bid >> 6) & 1;
  const int hc = bid >> 7;
  const int tid = threadIdx.x;

  const float* S    = (hc ? cT : hT) + (l * 64 + b) * 512;
  const float* muW  = (hc ? cmuW : hmuW) + l * 64 * 512;
  const float* mub  = (hc ? cmub : hmub) + l * 64;
  const float* sigW = (hc ? csigW : hsigW) + l * 64 * 512;
  const float* sigb = (hc ? csigb : hsigb) + l * 64;
  const float* outW = (hc ? coutW : houtW) + l * 512 * 64;
  const float* outb = (hc ? coutb : houtb) + l * 512;
  const float* eps  = (hc ? eps_c : eps_h) + (l * 64 + b) * 64;
  float* S2 = (hc ? c2 : h2) + (l * 64 + b) * 512;

  __shared__ float srow[512];
  __shared__ float z[64];
  srow[tid] = S[tid];
  __syncthreads();
  if (tid < 64) {
    const float* wm = muW + tid * 512;
    const float* ws = sigW + tid * 512;
    float mu = mub[tid], sg = sigb[tid];
    for (int d = 0; d < 512; ++d) {
      mu = fmaf(srow[d], wm[d], mu);
      sg = fmaf(srow[d], ws[d], sg);
    }
    z[tid] = mu + eps[tid] * sg;
    const size_t base = (size_t)64 * 512 * 512;
    const size_t idx = ((size_t)(hc * 2 + l) * 64 + b) * 64 + tid;
    out[base + idx] = mu;
    out[base + 4 * 64 * 64 + idx] = sg;
  }
  __syncthreads();
  {
    const float* wo = outW + tid * 64;
    float acc = outb[tid];
#pragma unroll 8
    for (int g = 0; g < 64; ++g) acc = fmaf(z[g], wo[g], acc);
    S2[tid] = acc;
  }
}

extern "C" void kernel_launch(void* const* d_in, const int* in_sizes, int n_in,
                              void* d_out, int out_size, void* d_ws, size_t ws_size,
                              hipStream_t stream) {
  const float* x      = (const float*)d_in[0];
  const float* initial= (const float*)d_in[1];
  const float* eWih   = (const float*)d_in[2];
  const float* eWhh   = (const float*)d_in[3];
  const float* ebih   = (const float*)d_in[4];
  const float* ebhh   = (const float*)d_in[5];
  const float* dWih   = (const float*)d_in[6];
  const float* dWhh   = (const float*)d_in[7];
  const float* dbih   = (const float*)d_in[8];
  const float* dbhh   = (const float*)d_in[9];
  const float* hmuW   = (const float*)d_in[10];
  const float* hmub   = (const float*)d_in[11];
  const float* hsigW  = (const float*)d_in[12];
  const float* hsigb  = (const float*)d_in[13];
  const float* houtW  = (const float*)d_in[14];
  const float* houtb  = (const float*)d_in[15];
  const float* cmuW   = (const float*)d_in[16];
  const float* cmub   = (const float*)d_in[17];
  const float* csigW  = (const float*)d_in[18];
  const float* csigb  = (const float*)d_in[19];
  const float* coutW  = (const float*)d_in[20];
  const float* coutb  = (const float*)d_in[21];
  const float* eps_h  = (const float*)d_in[22];
  const float* eps_c  = (const float*)d_in[23];

  char* ws = (char*)d_ws;
  bf16_t* enc_hbuf = (bf16_t*)(ws + OFF_ENC_HBUF);
  bf16_t* dec_hbuf = (bf16_t*)(ws + OFF_DEC_HBUF);
  bf16_t* dec_ybuf = (bf16_t*)(ws + OFF_DEC_YBUF);
  float* hT = (float*)(ws + OFF_HT);
  float* cT = (float*)(ws + OFF_CT);
  float* h2 = (float*)(ws + OFF_H2);
  float* c2 = (float*)(ws + OFF_C2);
  int* fe = (int*)(ws + OFF_FLAGS_E);
  int* fd = (int*)(ws + OFF_FLAGS_D);
  float* out = (float*)d_out;

  hipMemsetAsync(ws + OFF_FLAGS_E, 0, 2 * FLAGS_BYTES, stream);

  enc_pass<<<256, 256, 0, stream>>>(x, eWih, eWhh, ebih, ebhh, enc_hbuf, hT, cT, fe);
  vae_kernel<<<256, 512, 0, stream>>>(hT, cT, hmuW, hmub, hsigW, hsigb, houtW, houtb,
                                      cmuW, cmub, csigW, csigb, coutW, coutb,
                                      eps_h, eps_c, h2, c2, out);
  dec_pass<<<256, 256, 0, stream>>>(initial, dWih, dWhh, dbih, dbhh,
                                    h2, c2, dec_hbuf, dec_ybuf, out, fd);
}

// Round 4
// 5199.821 us; speedup vs baseline: 3.6032x; 1.4882x over previous
//
#include <hip/hip_runtime.h>
#include <hip/hip_bf16.h>

typedef __bf16 bf16_t;
typedef __attribute__((ext_vector_type(8))) __bf16 bf16x8;
typedef __attribute__((ext_vector_type(4))) float f32x4;
typedef __attribute__((ext_vector_type(4))) int i32x4;

#define MFMA16(a, b, c) __builtin_amdgcn_mfma_f32_16x16x32_bf16((a), (b), (c), 0, 0, 0)

namespace {
constexpr int TSEQ = 512, DDIM = 512, NB = 64;
constexpr size_t OFF_ENC_HBUF = 0;        // bf16 [2 layer][2 slot][64][512]
constexpr size_t OFF_DEC_HBUF = 262144;   // bf16 [2][2][64][512]
constexpr size_t OFF_DEC_YBUF = 524288;   // bf16 [2 slot][64][512]
constexpr size_t OFF_HT       = 655360;   // f32 [2][64][512]
constexpr size_t OFF_CT       = 917504;
constexpr size_t OFF_H2       = 1179648;
constexpr size_t OFF_C2       = 1441792;
constexpr int RETRY_CAP = 1 << 14;  // bounded spin: bug -> wrong answer, never a hang
template <int V> struct IC { static constexpr int v = V; };
}  // namespace

__device__ __forceinline__ float sigm_f(float x) { return 1.f / (1.f + __expf(-x)); }
__device__ __forceinline__ float tanh_f(float x) {
  x = fminf(15.f, fmaxf(-15.f, x));
  const float e = __expf(-2.f * x);
  return (1.f - e) / (1.f + e);
}
__device__ __forceinline__ bf16x8 cvt8(const float* __restrict__ p) {
  const float4 a = *(const float4*)p;
  const float4 b = *(const float4*)(p + 4);
  bf16x8 r;
  r[0] = (bf16_t)a.x; r[1] = (bf16_t)a.y; r[2] = (bf16_t)a.z; r[3] = (bf16_t)a.w;
  r[4] = (bf16_t)b.x; r[5] = (bf16_t)b.y; r[6] = (bf16_t)b.z; r[7] = (bf16_t)b.w;
  return r;
}

union FRAG { i32x4 i; bf16x8 v; };

// generation tag in the LSB of each bf16: tag(g) != tag(g+2); tag of every
// FIRST write to a slot is 1 (!= zeroed/0xAA-poisoned memory whose LSB is 0)
__device__ __forceinline__ unsigned tagpat(int g) {  // g >= -1
  return ((((g + 1) >> 1) & 1) ^ 1) ? 0x00010001u : 0u;
}
__device__ __forceinline__ unsigned chk4(const i32x4& v, unsigned pat) {
  unsigned bad = 0;
#pragma unroll
  for (int j = 0; j < 4; ++j) bad |= ((unsigned)v[j] ^ pat) & 0x00010001u;
  return bad;
}

// L1/L2-bypassing ops through L3 (the cross-XCD coherence point) — R2-proven
__device__ __forceinline__ void ldg_issue(const bf16_t* p, i32x4& d) {
  asm volatile("global_load_dwordx4 %0, %1, off sc0 sc1" : "=v"(d) : "v"(p) : "memory");
}
__device__ __forceinline__ void vm_wait0() {
  asm volatile("s_waitcnt vmcnt(0)" ::: "memory");
  __builtin_amdgcn_sched_barrier(0);  // keep tag-check / MFMA below the wait
}
__device__ __forceinline__ void stg_tag(bf16_t* p, float a, float b, unsigned pat) {
  union { bf16_t h[2]; unsigned u; } x;
  x.h[0] = (bf16_t)a; x.h[1] = (bf16_t)b;
  __hip_atomic_store((unsigned*)p, (x.u & ~0x00010001u) | pat,
                     __ATOMIC_RELAXED, __HIP_MEMORY_SCOPE_AGENT);
}

__device__ __forceinline__ void load_weights(const float* Wih, const float* Whh,
                                             int wave, int c15, int kg, int d0,
                                             bf16x8 (&wA)[2][8], bf16x8 (&wB)[2][8]) {
  const float* Wsrc = (wave < 2) ? Wih : Whh;
  const int kb = (wave & 1) << 8;
#pragma unroll
  for (int l = 0; l < 2; ++l)
#pragma unroll
    for (int nt = 0; nt < 2; ++nt)
#pragma unroll
      for (int ks = 0; ks < 8; ++ks) {
        const int n = nt * 16 + c15;
        const int grow = (n >> 3) * DDIM + d0 + (n & 7);
        const float* p = Wsrc + (size_t)(l * 2048 + grow) * DDIM + kb + ks * 32 + kg * 8;
        if (nt == 0) wA[l][ks] = cvt8(p);
        else         wB[l][ks] = cvt8(p);
      }
}

// ---------------- encoder: diagonal wavefront, 513 super-levels ----------------
__global__ __launch_bounds__(256, 1) void enc_pass(
    const float* __restrict__ x,
    const float* __restrict__ Wih, const float* __restrict__ Whh,
    const float* __restrict__ bih, const float* __restrict__ bhh,
    bf16_t* __restrict__ hbuf, float* __restrict__ hT, float* __restrict__ cT) {
  const int wg = blockIdx.x;
  const int grp = wg >> 6, slc = wg & 63;
  const int tid = threadIdx.x;
  const int wave = tid >> 6, lane = tid & 63;
  const int b0 = grp << 4, d0 = slc << 3;

  __shared__ float gbuf[2][4][16][33];
  __shared__ float bias_l[2][32];

  const int c15 = lane & 15, kg = lane >> 4;
  const int b = b0 + c15;

  bf16x8 wA[2][8], wB[2][8];
  load_weights(Wih, Whh, wave, c15, kg, d0, wA, wB);
  if (tid < 64) {
    const int l = tid >> 5, n = tid & 31;
    const int grow = (n >> 3) * DDIM + d0 + (n & 7);
    bias_l[l][n] = bih[l * 2048 + grow] + bhh[l * 2048 + grow];
  }
  if (tid < 128) {  // h0(-1)=0 -> slot1 (gen -1); h1(-1)=0 -> slot0 (gen 0); both tag=1
    const int l = tid >> 6, r6 = tid & 63, rw = r6 >> 2, dp = r6 & 3;
    const int slot = (l == 0) ? 1 : 0;
    stg_tag(&hbuf[((size_t)(l * 2 + slot) * NB + b0 + rw) * DDIM + d0 + 2 * dp],
            0.f, 0.f, 0x00010001u);
  }
  __syncthreads();

  float cA = 0.f, cB = 0.f;  // wave0: L0 c-state pair; wave1: L1 c-state pair

  for (int s = 0; s <= TSEQ; ++s) {
    const int p = s & 1, rp = p ^ 1;
    const unsigned patold = tagpat(s - 1);
    // -- pre-barrier: L0 x-half (external data, no sync needed) --
    f32x4 pa0 = {0.f, 0.f, 0.f, 0.f}, pa1 = {0.f, 0.f, 0.f, 0.f};
    if (wave < 2 && s < TSEQ) {
      const int kq = wave << 8;
      const float* ap = x + ((size_t)b * TSEQ + s) * DDIM + kq + kg * 8;
#pragma unroll
      for (int ks = 0; ks < 8; ++ks) {
        const bf16x8 a = cvt8(ap + ks * 32);
        pa0 = MFMA16(a, wA[0][ks], pa0);
        pa1 = MFMA16(a, wB[0][ks], pa1);
      }
    }
    __syncthreads();
    if (wave >= 2) {  // L0-recurrent (h0(s-1)) + L1-recurrent (h1(s-1)), tag-retry
      const int kq = (wave - 2) << 8;
      FRAG f0[8], f1[8];
      const bf16_t* a0p = hbuf + ((size_t)(0 * 2 + rp) * NB + b) * DDIM + kq + kg * 8;
      const bf16_t* a1p = hbuf + ((size_t)(1 * 2 + rp) * NB + b) * DDIM + kq + kg * 8;
      int guard = 0;
      for (;;) {
        if (s < TSEQ) {
#pragma unroll
          for (int ks = 0; ks < 8; ++ks) ldg_issue(a0p + ks * 32, f0[ks].i);
        }
        if (s >= 1) {
#pragma unroll
          for (int ks = 0; ks < 8; ++ks) ldg_issue(a1p + ks * 32, f1[ks].i);
        }
        vm_wait0();
        unsigned bad = 0;
        if (s < TSEQ) {
#pragma unroll
          for (int ks = 0; ks < 8; ++ks) bad |= chk4(f0[ks].i, patold);
        }
        if (s >= 1) {
#pragma unroll
          for (int ks = 0; ks < 8; ++ks) bad |= chk4(f1[ks].i, patold);
        }
        if (__all(bad == 0) || ++guard > RETRY_CAP) break;
      }
      if (s < TSEQ) {
        f32x4 a0 = {0.f, 0.f, 0.f, 0.f}, a1 = {0.f, 0.f, 0.f, 0.f};
#pragma unroll
        for (int ks = 0; ks < 8; ++ks) {
          a0 = MFMA16(f0[ks].v, wA[0][ks], a0);
          a1 = MFMA16(f0[ks].v, wB[0][ks], a1);
        }
#pragma unroll
        for (int r = 0; r < 4; ++r) {
          gbuf[0][wave][kg * 4 + r][c15] = a0[r];
          gbuf[0][wave][kg * 4 + r][16 + c15] = a1[r];
        }
      }
      if (s >= 1) {
        f32x4 a0 = {0.f, 0.f, 0.f, 0.f}, a1 = {0.f, 0.f, 0.f, 0.f};
#pragma unroll
        for (int ks = 0; ks < 8; ++ks) {
          a0 = MFMA16(f1[ks].v, wA[1][ks], a0);
          a1 = MFMA16(f1[ks].v, wB[1][ks], a1);
        }
#pragma unroll
        for (int r = 0; r < 4; ++r) {
          gbuf[1][wave][kg * 4 + r][c15] = a0[r];
          gbuf[1][wave][kg * 4 + r][16 + c15] = a1[r];
        }
      }
    } else {
      if (s < TSEQ) {  // commit x-half accumulators (post-barrier: race-safe)
#pragma unroll
        for (int r = 0; r < 4; ++r) {
          gbuf[0][wave][kg * 4 + r][c15] = pa0[r];
          gbuf[0][wave][kg * 4 + r][16 + c15] = pa1[r];
        }
      }
      if (s >= 1) {  // L1 input half: A = h0(s-1), tag-retry
        const int kq = wave << 8;
        FRAG f[8];
        const bf16_t* ap = hbuf + ((size_t)(0 * 2 + rp) * NB + b) * DDIM + kq + kg * 8;
        int guard = 0;
        for (;;) {
#pragma unroll
          for (int ks = 0; ks < 8; ++ks) ldg_issue(ap + ks * 32, f[ks].i);
          vm_wait0();
          unsigned bad = 0;
#pragma unroll
          for (int ks = 0; ks < 8; ++ks) bad |= chk4(f[ks].i, patold);
          if (__all(bad == 0) || ++guard > RETRY_CAP) break;
        }
        f32x4 a0 = {0.f, 0.f, 0.f, 0.f}, a1 = {0.f, 0.f, 0.f, 0.f};
#pragma unroll
        for (int ks = 0; ks < 8; ++ks) {
          a0 = MFMA16(f[ks].v, wA[1][ks], a0);
          a1 = MFMA16(f[ks].v, wB[1][ks], a1);
        }
#pragma unroll
        for (int r = 0; r < 4; ++r) {
          gbuf[1][wave][kg * 4 + r][c15] = a0[r];
          gbuf[1][wave][kg * 4 + r][16 + c15] = a1[r];
        }
      }
    }
    __syncthreads();
    // -- epilogue: wave0 -> L0, wave1 -> L1; stores carry tag(s) --
    if (tid < 128) {
      const int ll = tid >> 6, r6 = tid & 63, rw = r6 >> 2, dp = r6 & 3;
      const bool act = (ll == 0) ? (s < TSEQ) : (s >= 1);
      if (act) {
        const unsigned pat = tagpat(s);
        float hv2[2], cv2[2];
#pragma unroll
        for (int e2 = 0; e2 < 2; ++e2) {
          const int e = dp * 2 + e2;
          float gi = bias_l[ll][e],      gf = bias_l[ll][8 + e];
          float gg = bias_l[ll][16 + e], go = bias_l[ll][24 + e];
#pragma unroll
          for (int q = 0; q < 4; ++q) {
            gi += gbuf[ll][q][rw][e];
            gf += gbuf[ll][q][rw][8 + e];
            gg += gbuf[ll][q][rw][16 + e];
            go += gbuf[ll][q][rw][24 + e];
          }
          const float iv = sigm_f(gi), fv = sigm_f(gf), gv = tanh_f(gg), ov = sigm_f(go);
          float& cs = (e2 == 0) ? cA : cB;
          cs = fv * cs + iv * gv;
          cv2[e2] = cs;
          hv2[e2] = ov * tanh_f(cs);
        }
        const int b2 = b0 + rw, dc = d0 + dp * 2;
        stg_tag(&hbuf[((size_t)(ll * 2 + p) * NB + b2) * DDIM + dc], hv2[0], hv2[1], pat);
        if ((ll == 0 && s == TSEQ - 1) || (ll == 1 && s == TSEQ)) {
          *(float2*)&hT[((size_t)ll * NB + b2) * DDIM + dc] = float2{hv2[0], hv2[1]};
          *(float2*)&cT[((size_t)ll * NB + b2) * DDIM + dc] = float2{cv2[0], cv2[1]};
        }
      }
    }
  }
}

// ---------------- decoder: serial chain, 1024 levels ----------------
__global__ __launch_bounds__(256, 1) void dec_pass(
    const float* __restrict__ initial,
    const float* __restrict__ Wih, const float* __restrict__ Whh,
    const float* __restrict__ bih, const float* __restrict__ bhh,
    const float* __restrict__ h_init, const float* __restrict__ c_init,
    bf16_t* __restrict__ hbuf, bf16_t* __restrict__ ybuf,
    float* __restrict__ out) {
  const int wg = blockIdx.x;
  const int grp = wg >> 6, slc = wg & 63;
  const int tid = threadIdx.x;
  const int wave = tid >> 6, lane = tid & 63;
  const int b0 = grp << 4, d0 = slc << 3;

  __shared__ float gbuf[4][16][33];
  __shared__ float bias_l[2][32];

  const int c15 = lane & 15, kg = lane >> 4;
  const int b = b0 + c15;

  bf16x8 wA[2][8], wB[2][8];
  load_weights(Wih, Whh, wave, c15, kg, d0, wA, wB);
  if (tid < 64) {
    const int l = tid >> 5, n = tid & 31;
    const int grow = (n >> 3) * DDIM + d0 + (n & 7);
    bias_l[l][n] = bih[l * 2048 + grow] + bhh[l * 2048 + grow];
  }
  if (tid < 128) {  // h_init -> slot1 (gen -1, tag 1)
    const int l = tid >> 6, r6 = tid & 63, rw = r6 >> 2, dp = r6 & 3;
    const int b2 = b0 + rw, dc = d0 + 2 * dp;
    const float2 hv = *(const float2*)&h_init[((size_t)l * NB + b2) * DDIM + dc];
    stg_tag(&hbuf[((size_t)(l * 2 + 1) * NB + b2) * DDIM + dc], hv.x, hv.y, 0x00010001u);
  }
  if (tid < 64) {  // y(-1)=initial -> slot1 (gen -1, tag 1)
    const int rw = tid >> 2, dp = tid & 3;
    const int dc = d0 + 2 * dp;
    stg_tag(&ybuf[((size_t)1 * NB + b0 + rw) * DDIM + dc], initial[dc], initial[dc + 1],
            0x00010001u);
  }
  const int rw0 = lane >> 2, dp0 = lane & 3;
  float cA0 = 0.f, cB0 = 0.f, cA1 = 0.f, cB1 = 0.f;
  if (wave == 0) {
    const float2 c0 = *(const float2*)&c_init[((size_t)0 * NB + b0 + rw0) * DDIM + d0 + 2 * dp0];
    const float2 c1 = *(const float2*)&c_init[((size_t)1 * NB + b0 + rw0) * DDIM + d0 + 2 * dp0];
    cA0 = c0.x; cB0 = c0.y; cA1 = c1.x; cB1 = c1.y;
  }
  __syncthreads();

  auto level = [&](auto lcc, const int t, const int p, const int rp) {
    constexpr int LC = decltype(lcc)::v;
    const unsigned patold = tagpat(t - 1);
    f32x4 pa0 = {0.f, 0.f, 0.f, 0.f}, pa1 = {0.f, 0.f, 0.f, 0.f};
    // -- pre-barrier: recurrent half h_LC(t-1) (tag-retry; covers init race) --
    if (wave >= 2) {
      const int kq = (wave - 2) << 8;
      FRAG f[8];
      const bf16_t* ap = hbuf + ((size_t)(LC * 2 + rp) * NB + b) * DDIM + kq + kg * 8;
      int guard = 0;
      for (;;) {
#pragma unroll
        for (int ks = 0; ks < 8; ++ks) ldg_issue(ap + ks * 32, f[ks].i);
        vm_wait0();
        unsigned bad = 0;
#pragma unroll
        for (int ks = 0; ks < 8; ++ks) bad |= chk4(f[ks].i, patold);
        if (__all(bad == 0) || ++guard > RETRY_CAP) break;
      }
#pragma unroll
      for (int ks = 0; ks < 8; ++ks) {
        pa0 = MFMA16(f[ks].v, wA[LC][ks], pa0);
        pa1 = MFMA16(f[ks].v, wB[LC][ks], pa1);
      }
    }
    __syncthreads();
    if (wave >= 2) {
#pragma unroll
      for (int r = 0; r < 4; ++r) {
        gbuf[wave][kg * 4 + r][c15] = pa0[r];
        gbuf[wave][kg * 4 + r][16 + c15] = pa1[r];
      }
    } else {  // fresh half: L0 reads y(t-1) [gen t-1]; L1 reads h0(t) [gen t]
      const int kq = wave << 8;
      const unsigned patf = (LC == 0) ? patold : tagpat(t);
      const bf16_t* base = (LC == 0) ? (ybuf + (size_t)rp * NB * DDIM)
                                     : (hbuf + (size_t)(0 * 2 + p) * NB * DDIM);
      const bf16_t* ap = base + (size_t)b * DDIM + kq + kg * 8;
      FRAG f[8];
      int guard = 0;
      for (;;) {
#pragma unroll
        for (int ks = 0; ks < 8; ++ks) ldg_issue(ap + ks * 32, f[ks].i);
        vm_wait0();
        unsigned bad = 0;
#pragma unroll
        for (int ks = 0; ks < 8; ++ks) bad |= chk4(f[ks].i, patf);
        if (__all(bad == 0) || ++guard > RETRY_CAP) break;
      }
      f32x4 a0 = {0.f, 0.f, 0.f, 0.f}, a1 = {0.f, 0.f, 0.f, 0.f};
#pragma unroll
      for (int ks = 0; ks < 8; ++ks) {
        a0 = MFMA16(f[ks].v, wA[LC][ks], a0);
        a1 = MFMA16(f[ks].v, wB[LC][ks], a1);
      }
#pragma unroll
      for (int r = 0; r < 4; ++r) {
        gbuf[wave][kg * 4 + r][c15] = a0[r];
        gbuf[wave][kg * 4 + r][16 + c15] = a1[r];
      }
    }
    __syncthreads();
    // -- epilogue (wave0): h/y stores carry tag(t) --
    if (tid < 64) {
      const unsigned pat = tagpat(t);
      float hv2[2];
#pragma unroll
      for (int e2 = 0; e2 < 2; ++e2) {
        const int e = dp0 * 2 + e2;
        float gi = bias_l[LC][e],      gf = bias_l[LC][8 + e];
        float gg = bias_l[LC][16 + e], go = bias_l[LC][24 + e];
#pragma unroll
        for (int q = 0; q < 4; ++q) {
          gi += gbuf[q][rw0][e];
          gf += gbuf[q][rw0][8 + e];
          gg += gbuf[q][rw0][16 + e];
          go += gbuf[q][rw0][24 + e];
        }
        const float iv = sigm_f(gi), fv = sigm_f(gf), gv = tanh_f(gg), ov = sigm_f(go);
        float& cs = (LC == 0) ? ((e2 == 0) ? cA0 : cB0) : ((e2 == 0) ? cA1 : cB1);
        cs = fv * cs + iv * gv;
        hv2[e2] = ov * tanh_f(cs);
      }
      const int b2 = b0 + rw0, dc = d0 + dp0 * 2;
      stg_tag(&hbuf[((size_t)(LC * 2 + p) * NB + b2) * DDIM + dc], hv2[0], hv2[1], pat);
      if (LC == 1) {
        stg_tag(&ybuf[((size_t)p * NB + b2) * DDIM + dc], hv2[0], hv2[1], pat);
        *(float2*)&out[((size_t)b2 * TSEQ + t) * DDIM + dc] = float2{hv2[0], hv2[1]};
      }
    }
  };

  for (int t = 0; t < TSEQ; ++t) {
    const int p = t & 1, rp = p ^ 1;
    level(IC<0>{}, t, p, rp);
    level(IC<1>{}, t, p, rp);
  }
}

__global__ __launch_bounds__(512) void vae_kernel(
    const float* __restrict__ hT, const float* __restrict__ cT,
    const float* __restrict__ hmuW, const float* __restrict__ hmub,
    const float* __restrict__ hsigW, const float* __restrict__ hsigb,
    const float* __restrict__ houtW, const float* __restrict__ houtb,
    const float* __restrict__ cmuW, const float* __restrict__ cmub,
    const float* __restrict__ csigW, const float* __restrict__ csigb,
    const float* __restrict__ coutW, const float* __restrict__ coutb,
    const float* __restrict__ eps_h, const float* __restrict__ eps_c,
    float* __restrict__ h2, float* __restrict__ c2, float* __restrict__ out) {
  const int bid = blockIdx.x;  // (hc, layer, b)
  const int b = bid & 63;
  const int l = (bid >> 6) & 1;
  const int hc = bid >> 7;
  const int tid = threadIdx.x;

  const float* S    = (hc ? cT : hT) + (l * 64 + b) * 512;
  const float* muW  = (hc ? cmuW : hmuW) + l * 64 * 512;
  const float* mub  = (hc ? cmub : hmub) + l * 64;
  const float* sigW = (hc ? csigW : hsigW) + l * 64 * 512;
  const float* sigb = (hc ? csigb : hsigb) + l * 64;
  const float* outW = (hc ? coutW : houtW) + l * 512 * 64;
  const float* outb = (hc ? coutb : houtb) + l * 512;
  const float* eps  = (hc ? eps_c : eps_h) + (l * 64 + b) * 64;
  float* S2 = (hc ? c2 : h2) + (l * 64 + b) * 512;

  __shared__ float srow[512];
  __shared__ float z[64];
  srow[tid] = S[tid];
  __syncthreads();
  if (tid < 64) {
    const float* wm = muW + tid * 512;
    const float* ws = sigW + tid * 512;
    float mu = mub[tid], sg = sigb[tid];
    for (int d = 0; d < 512; ++d) {
      mu = fmaf(srow[d], wm[d], mu);
      sg = fmaf(srow[d], ws[d], sg);
    }
    z[tid] = mu + eps[tid] * sg;
    const size_t base = (size_t)64 * 512 * 512;
    const size_t idx = ((size_t)(hc * 2 + l) * 64 + b) * 64 + tid;
    out[base + idx] = mu;
    out[base + 4 * 64 * 64 + idx] = sg;
  }
  __syncthreads();
  {
    const float* wo = outW + tid * 64;
    float acc = outb[tid];
#pragma unroll 8
    for (int g = 0; g < 64; ++g) acc = fmaf(z[g], wo[g], acc);
    S2[tid] = acc;
  }
}

extern "C" void kernel_launch(void* const* d_in, const int* in_sizes, int n_in,
                              void* d_out, int out_size, void* d_ws, size_t ws_size,
                              hipStream_t stream) {
  const float* x       = (const float*)d_in[0];
  const float* initial = (const float*)d_in[1];
  const float* eWih    = (const float*)d_in[2];
  const float* eWhh    = (const float*)d_in[3];
  const float* ebih    = (const float*)d_in[4];
  const float* ebhh    = (const float*)d_in[5];
  const float* dWih    = (const float*)d_in[6];
  const float* dWhh    = (const float*)d_in[7];
  const float* dbih    = (const float*)d_in[8];
  const float* dbhh    = (const float*)d_in[9];
  const float* hmuW    = (const float*)d_in[10];
  const float* hmub    = (const float*)d_in[11];
  const float* hsigW   = (const float*)d_in[12];
  const float* hsigb   = (const float*)d_in[13];
  const float* houtW   = (const float*)d_in[14];
  const float* houtb   = (const float*)d_in[15];
  const float* cmuW    = (const float*)d_in[16];
  const float* cmub    = (const float*)d_in[17];
  const float* csigW   = (const float*)d_in[18];
  const float* csigb   = (const float*)d_in[19];
  const float* coutW   = (const float*)d_in[20];
  const float* coutb   = (const float*)d_in[21];
  const float* eps_h   = (const float*)d_in[22];
  const float* eps_c   = (const float*)d_in[23];

  char* ws = (char*)d_ws;
  bf16_t* enc_hbuf = (bf16_t*)(ws + OFF_ENC_HBUF);
  bf16_t* dec_hbuf = (bf16_t*)(ws + OFF_DEC_HBUF);
  bf16_t* dec_ybuf = (bf16_t*)(ws + OFF_DEC_YBUF);
  float* hT = (float*)(ws + OFF_HT);
  float* cT = (float*)(ws + OFF_CT);
  float* h2 = (float*)(ws + OFF_H2);
  float* c2 = (float*)(ws + OFF_C2);
  float* out = (float*)d_out;

  // zero all exchange buffers every call: tag LSB of unwritten data must be 0
  hipMemsetAsync(ws, 0, OFF_HT, stream);

  enc_pass<<<256, 256, 0, stream>>>(x, eWih, eWhh, ebih, ebhh, enc_hbuf, hT, cT);
  vae_kernel<<<256, 512, 0, stream>>>(hT, cT, hmuW, hmub, hsigW, hsigb, houtW, houtb,
                                      cmuW, cmub, csigW, csigb, coutW, coutb,
                                      eps_h, eps_c, h2, c2, out);
  dec_pass<<<256, 256, 0, stream>>>(initial, dWih, dWhh, dbih, dbhh,
                                    h2, c2, dec_hbuf, dec_ybuf, out);
}

// Round 6
// 4917.590 us; speedup vs baseline: 3.8100x; 1.0574x over previous
//
#include <hip/hip_runtime.h>
#include <hip/hip_bf16.h>

typedef __bf16 bf16_t;
typedef __attribute__((ext_vector_type(8))) __bf16 bf16x8;
typedef __attribute__((ext_vector_type(4))) float f32x4;
typedef __attribute__((ext_vector_type(4))) int i32x4;

#define MFMA16(a, b, c) __builtin_amdgcn_mfma_f32_16x16x32_bf16((a), (b), (c), 0, 0, 0)

namespace {
constexpr int TSEQ = 512, DDIM = 512, NB = 64;
constexpr size_t OFF_ENC_HBUF = 0;        // bf16 [2 layer][2 slot][64][512]
constexpr size_t OFF_DEC_HBUF = 262144;   // bf16 [2][2][64][512]
constexpr size_t OFF_DEC_YBUF = 524288;   // bf16 [2 slot][64][512]
constexpr size_t OFF_HT       = 655360;   // f32 [2][64][512]
constexpr size_t OFF_CT       = 917504;
constexpr size_t OFF_H2       = 1179648;
constexpr size_t OFF_C2       = 1441792;
constexpr size_t OFF_GX       = 2097152;  // u32 [512 t][256 wg][256] fp16x2
constexpr size_t GX_BYTES     = (size_t)512 * 256 * 256 * 4;  // 134 MB
constexpr int RETRY_CAP = 1 << 14;  // bounded spin: bug -> wrong answer, never a hang
template <int V> struct IC { static constexpr int v = V; };
}  // namespace

__device__ __forceinline__ float sigm_f(float x) { return 1.f / (1.f + __expf(-x)); }
__device__ __forceinline__ float tanh_f(float x) {
  x = fminf(15.f, fmaxf(-15.f, x));
  const float e = __expf(-2.f * x);
  return (1.f - e) / (1.f + e);
}
__device__ __forceinline__ bf16x8 cvt8(const float* __restrict__ p) {
  const float4 a = *(const float4*)p;
  const float4 b = *(const float4*)(p + 4);
  bf16x8 r;
  r[0] = (bf16_t)a.x; r[1] = (bf16_t)a.y; r[2] = (bf16_t)a.z; r[3] = (bf16_t)a.w;
  r[4] = (bf16_t)b.x; r[5] = (bf16_t)b.y; r[6] = (bf16_t)b.z; r[7] = (bf16_t)b.w;
  return r;
}

union FRAG { i32x4 i; bf16x8 v; };

// generation tag in the LSB of each bf16: tag(g) != tag(g+2); tag of every
// FIRST write to a slot is 1 (!= zeroed/0xAA-poisoned memory whose LSB is 0)
__device__ __forceinline__ unsigned tagpat(int g) {  // g >= -1
  return ((((g + 1) >> 1) & 1) ^ 1) ? 0x00010001u : 0u;
}
__device__ __forceinline__ unsigned chk4(const i32x4& v, unsigned pat) {
  unsigned bad = 0;
#pragma unroll
  for (int j = 0; j < 4; ++j) bad |= ((unsigned)v[j] ^ pat) & 0x00010001u;
  return bad;
}

// L1/L2-bypassing ops through L3 (the cross-XCD coherence point) — R2/R4-proven
__device__ __forceinline__ void ldg_issue(const bf16_t* p, i32x4& d) {
  asm volatile("global_load_dwordx4 %0, %1, off sc0 sc1" : "=v"(d) : "v"(p) : "memory");
}
__device__ __forceinline__ void vm_wait0() {
  asm volatile("s_waitcnt vmcnt(0)" ::: "memory");
  __builtin_amdgcn_sched_barrier(0);  // keep tag-check / MFMA below the wait
}
__device__ __forceinline__ void stg_tag(bf16_t* p, float a, float b, unsigned pat) {
  union { bf16_t h[2]; unsigned u; } x;
  x.h[0] = (bf16_t)a; x.h[1] = (bf16_t)b;
  __hip_atomic_store((unsigned*)p, (x.u & ~0x00010001u) | pat,
                     __ATOMIC_RELAXED, __HIP_MEMORY_SCOPE_AGENT);
}

__device__ __forceinline__ void load_weights(const float* Wih, const float* Whh,
                                             int wave, int c15, int kg, int d0,
                                             bf16x8 (&wA)[2][8], bf16x8 (&wB)[2][8]) {
  const float* Wsrc = (wave < 2) ? Wih : Whh;
  const int kb = (wave & 1) << 8;
#pragma unroll
  for (int l = 0; l < 2; ++l)
#pragma unroll
    for (int nt = 0; nt < 2; ++nt)
#pragma unroll
      for (int ks = 0; ks < 8; ++ks) {
        const int n = nt * 16 + c15;
        const int grow = (n >> 3) * DDIM + d0 + (n & 7);
        const float* p = Wsrc + (size_t)(l * 2048 + grow) * DDIM + kb + ks * 32 + kg * 8;
        if (nt == 0) wA[l][ks] = cvt8(p);
        else         wB[l][ks] = cvt8(p);
      }
}

// ---------------- pre-pass: gx[t] = x_t @ Wih0^T (fp16), fully parallel ----------------
__global__ __launch_bounds__(256, 4) void gx_pass(
    const float* __restrict__ x, const float* __restrict__ Wih,
    unsigned* __restrict__ gx) {
  const int wg0 = blockIdx.x & 255;   // same (grp,slc) mapping as enc_pass
  const int tc  = blockIdx.x >> 8;    // 0..7, 64 timesteps each
  const int grp = wg0 >> 6, slc = wg0 & 63;
  const int tid = threadIdx.x;
  const int wave = tid >> 6, lane = tid & 63;
  const int c15 = lane & 15, kg = lane >> 4;
  const int b0 = grp << 4, d0 = slc << 3;
  const int kb = (wave & 1) << 8;   // K-half, exactly like enc x-path
  const int tpar = wave >> 1;       // waves 0-1 -> even t, 2-3 -> odd t

  __shared__ float gbuf[2][2][16][33];

  bf16x8 wA[8], wB[8];  // layer-0 Wih fragments only
#pragma unroll
  for (int nt = 0; nt < 2; ++nt)
#pragma unroll
    for (int ks = 0; ks < 8; ++ks) {
      const int n = nt * 16 + c15;
      const int grow = (n >> 3) * DDIM + d0 + (n & 7);
      const float* p = Wih + (size_t)grow * DDIM + kb + ks * 32 + kg * 8;
      if (nt == 0) wA[ks] = cvt8(p);
      else         wB[ks] = cvt8(p);
    }

  const int b = b0 + c15;
  for (int j = 0; j < 32; ++j) {
    const int t = tc * 64 + 2 * j + tpar;
    f32x4 a0 = {0.f, 0.f, 0.f, 0.f}, a1 = {0.f, 0.f, 0.f, 0.f};
    const float* ap = x + ((size_t)b * TSEQ + t) * DDIM + kb + kg * 8;
#pragma unroll
    for (int ks = 0; ks < 8; ++ks) {
      const bf16x8 a = cvt8(ap + ks * 32);  // identical convert path to R4 enc
      a0 = MFMA16(a, wA[ks], a0);
      a1 = MFMA16(a, wB[ks], a1);
    }
#pragma unroll
    for (int r = 0; r < 4; ++r) {
      gbuf[tpar][wave & 1][kg * 4 + r][c15] = a0[r];
      gbuf[tpar][wave & 1][kg * 4 + r][16 + c15] = a1[r];
    }
    __syncthreads();
    if (tid < 128) {
      const int ll = tid >> 6, r6 = tid & 63, rw = r6 >> 2, dp = r6 & 3;
      const int tt = tc * 64 + 2 * j + ll;
      const size_t base = ((size_t)tt * 256 + wg0) * 256 + rw * 16 + dp;
#pragma unroll
      for (int g = 0; g < 4; ++g) {
        const int e = g * 8 + 2 * dp;
        const float v0 = gbuf[ll][0][rw][e] + gbuf[ll][1][rw][e];
        const float v1 = gbuf[ll][0][rw][e + 1] + gbuf[ll][1][rw][e + 1];
        union { _Float16 h[2]; unsigned u; } pk;
        pk.h[0] = (_Float16)v0; pk.h[1] = (_Float16)v1;
        gx[base + g * 4] = pk.u;
      }
    }
    __syncthreads();
  }
}

// ---------------- encoder: diagonal wavefront; GX=1 reads precomputed x-half ----------------
template <int GX>
__global__ __launch_bounds__(256, 1) void enc_pass(
    const float* __restrict__ x,
    const float* __restrict__ Wih, const float* __restrict__ Whh,
    const float* __restrict__ bih, const float* __restrict__ bhh,
    bf16_t* __restrict__ hbuf, float* __restrict__ hT, float* __restrict__ cT,
    const unsigned* __restrict__ gx) {
  const int wg = blockIdx.x;
  const int grp = wg >> 6, slc = wg & 63;
  const int tid = threadIdx.x;
  const int wave = tid >> 6, lane = tid & 63;
  const int b0 = grp << 4, d0 = slc << 3;

  __shared__ float gbuf[2][4][16][33];
  __shared__ float bias_l[2][32];

  const int c15 = lane & 15, kg = lane >> 4;
  const int b = b0 + c15;

  bf16x8 wA[2][8], wB[2][8];
  load_weights(Wih, Whh, wave, c15, kg, d0, wA, wB);
  if (tid < 64) {
    const int l = tid >> 5, n = tid & 31;
    const int grow = (n >> 3) * DDIM + d0 + (n & 7);
    bias_l[l][n] = bih[l * 2048 + grow] + bhh[l * 2048 + grow];
  }
  if (tid < 128) {  // h0(-1)=0 -> slot1 (gen -1); h1(-1)=0 -> slot0 (gen 0); both tag=1
    const int l = tid >> 6, r6 = tid & 63, rw = r6 >> 2, dp = r6 & 3;
    const int slot = (l == 0) ? 1 : 0;
    stg_tag(&hbuf[((size_t)(l * 2 + slot) * NB + b0 + rw) * DDIM + d0 + 2 * dp],
            0.f, 0.f, 0x00010001u);
  }
  __syncthreads();

  float cA = 0.f, cB = 0.f;  // wave0: L0 c-state pair; wave1: L1 c-state pair

  for (int s = 0; s <= TSEQ; ++s) {
    const int p = s & 1, rp = p ^ 1;
    const unsigned patold = tagpat(s - 1);
    // -- pre-barrier: L0 x-half --
    f32x4 pa0 = {0.f, 0.f, 0.f, 0.f}, pa1 = {0.f, 0.f, 0.f, 0.f};
    unsigned gxr[4];
    if constexpr (GX) {
      if (tid < 64 && s < TSEQ) {  // 4 plain cached loads; latency hides under retry
        const size_t base = ((size_t)s * 256 + wg) * 256 + (tid >> 2) * 16 + (tid & 3);
#pragma unroll
        for (int g = 0; g < 4; ++g) gxr[g] = gx[base + g * 4];
      }
    } else {
      if (wave < 2 && s < TSEQ) {
        const int kq = wave << 8;
        const float* ap = x + ((size_t)b * TSEQ + s) * DDIM + kq + kg * 8;
#pragma unroll
        for (int ks = 0; ks < 8; ++ks) {
          const bf16x8 a = cvt8(ap + ks * 32);
          pa0 = MFMA16(a, wA[0][ks], pa0);
          pa1 = MFMA16(a, wB[0][ks], pa1);
        }
      }
    }
    __syncthreads();
    if (wave >= 2) {  // L0-recurrent (h0(s-1)) + L1-recurrent (h1(s-1)), tag-retry
      const int kq = (wave - 2) << 8;
      FRAG f0[8], f1[8];
      const bf16_t* a0p = hbuf + ((size_t)(0 * 2 + rp) * NB + b) * DDIM + kq + kg * 8;
      const bf16_t* a1p = hbuf + ((size_t)(1 * 2 + rp) * NB + b) * DDIM + kq + kg * 8;
      int guard = 0;
      for (;;) {
        if (s < TSEQ) {
#pragma unroll
          for (int ks = 0; ks < 8; ++ks) ldg_issue(a0p + ks * 32, f0[ks].i);
        }
        if (s >= 1) {
#pragma unroll
          for (int ks = 0; ks < 8; ++ks) ldg_issue(a1p + ks * 32, f1[ks].i);
        }
        vm_wait0();
        unsigned bad = 0;
        if (s < TSEQ) {
#pragma unroll
          for (int ks = 0; ks < 8; ++ks) bad |= chk4(f0[ks].i, patold);
        }
        if (s >= 1) {
#pragma unroll
          for (int ks = 0; ks < 8; ++ks) bad |= chk4(f1[ks].i, patold);
        }
        if (__all(bad == 0) || ++guard > RETRY_CAP) break;
      }
      if (s < TSEQ) {
        f32x4 a0 = {0.f, 0.f, 0.f, 0.f}, a1 = {0.f, 0.f, 0.f, 0.f};
#pragma unroll
        for (int ks = 0; ks < 8; ++ks) {
          a0 = MFMA16(f0[ks].v, wA[0][ks], a0);
          a1 = MFMA16(f0[ks].v, wB[0][ks], a1);
        }
#pragma unroll
        for (int r = 0; r < 4; ++r) {
          gbuf[0][wave][kg * 4 + r][c15] = a0[r];
          gbuf[0][wave][kg * 4 + r][16 + c15] = a1[r];
        }
      }
      if (s >= 1) {
        f32x4 a0 = {0.f, 0.f, 0.f, 0.f}, a1 = {0.f, 0.f, 0.f, 0.f};
#pragma unroll
        for (int ks = 0; ks < 8; ++ks) {
          a0 = MFMA16(f1[ks].v, wA[1][ks], a0);
          a1 = MFMA16(f1[ks].v, wB[1][ks], a1);
        }
#pragma unroll
        for (int r = 0; r < 4; ++r) {
          gbuf[1][wave][kg * 4 + r][c15] = a0[r];
          gbuf[1][wave][kg * 4 + r][16 + c15] = a1[r];
        }
      }
    } else {
      if constexpr (!GX) {
        if (s < TSEQ) {  // commit x-half accumulators (post-barrier: race-safe)
#pragma unroll
          for (int r = 0; r < 4; ++r) {
            gbuf[0][wave][kg * 4 + r][c15] = pa0[r];
            gbuf[0][wave][kg * 4 + r][16 + c15] = pa1[r];
          }
        }
      }
      if (s >= 1) {  // L1 input half: A = h0(s-1), tag-retry
        const int kq = wave << 8;
        FRAG f[8];
        const bf16_t* ap = hbuf + ((size_t)(0 * 2 + rp) * NB + b) * DDIM + kq + kg * 8;
        int guard = 0;
        for (;;) {
#pragma unroll
          for (int ks = 0; ks < 8; ++ks) ldg_issue(ap + ks * 32, f[ks].i);
          vm_wait0();
          unsigned bad = 0;
#pragma unroll
          for (int ks = 0; ks < 8; ++ks) bad |= chk4(f[ks].i, patold);
          if (__all(bad == 0) || ++guard > RETRY_CAP) break;
        }
        f32x4 a0 = {0.f, 0.f, 0.f, 0.f}, a1 = {0.f, 0.f, 0.f, 0.f};
#pragma unroll
        for (int ks = 0; ks < 8; ++ks) {
          a0 = MFMA16(f[ks].v, wA[1][ks], a0);
          a1 = MFMA16(f[ks].v, wB[1][ks], a1);
        }
#pragma unroll
        for (int r = 0; r < 4; ++r) {
          gbuf[1][wave][kg * 4 + r][c15] = a0[r];
          gbuf[1][wave][kg * 4 + r][16 + c15] = a1[r];
        }
      }
    }
    __syncthreads();
    // -- epilogue: wave0 -> L0, wave1 -> L1; stores carry tag(s) --
    if (tid < 128) {
      const int ll = tid >> 6, r6 = tid & 63, rw = r6 >> 2, dp = r6 & 3;
      const bool act = (ll == 0) ? (s < TSEQ) : (s >= 1);
      if (act) {
        const unsigned pat = tagpat(s);
        float gs[4][2];
#pragma unroll
        for (int g = 0; g < 4; ++g) {
          gs[g][0] = bias_l[ll][g * 8 + 2 * dp];
          gs[g][1] = bias_l[ll][g * 8 + 2 * dp + 1];
        }
        if (GX && ll == 0) {
#pragma unroll
          for (int g = 0; g < 4; ++g) {
            union { unsigned u; _Float16 h[2]; } dk;
            dk.u = gxr[g];
            gs[g][0] += (float)dk.h[0];
            gs[g][1] += (float)dk.h[1];
          }
        }
        const int q0 = (GX && ll == 0) ? 2 : 0;
#pragma unroll
        for (int q = 0; q < 4; ++q) {
          if (q >= q0) {
#pragma unroll
            for (int g = 0; g < 4; ++g) {
              const int e = g * 8 + 2 * dp;
              gs[g][0] += gbuf[ll][q][rw][e];
              gs[g][1] += gbuf[ll][q][rw][e + 1];
            }
          }
        }
        float hv2[2], cv2[2];
#pragma unroll
        for (int e2 = 0; e2 < 2; ++e2) {
          const float iv = sigm_f(gs[0][e2]), fv = sigm_f(gs[1][e2]);
          const float gv = tanh_f(gs[2][e2]), ov = sigm_f(gs[3][e2]);
          float& cs = (e2 == 0) ? cA : cB;
          cs = fv * cs + iv * gv;
          cv2[e2] = cs;
          hv2[e2] = ov * tanh_f(cs);
        }
        const int b2 = b0 + rw, dc = d0 + dp * 2;
        stg_tag(&hbuf[((size_t)(ll * 2 + p) * NB + b2) * DDIM + dc], hv2[0], hv2[1], pat);
        if ((ll == 0 && s == TSEQ - 1) || (ll == 1 && s == TSEQ)) {
          *(float2*)&hT[((size_t)ll * NB + b2) * DDIM + dc] = float2{hv2[0], hv2[1]};
          *(float2*)&cT[((size_t)ll * NB + b2) * DDIM + dc] = float2{cv2[0], cv2[1]};
        }
      }
    }
  }
}

// ---------------- decoder: serial chain, 1024 levels (R4-proven, unchanged) ----------------
__global__ __launch_bounds__(256, 1) void dec_pass(
    const float* __restrict__ initial,
    const float* __restrict__ Wih, const float* __restrict__ Whh,
    const float* __restrict__ bih, const float* __restrict__ bhh,
    const float* __restrict__ h_init, const float* __restrict__ c_init,
    bf16_t* __restrict__ hbuf, bf16_t* __restrict__ ybuf,
    float* __restrict__ out) {
  const int wg = blockIdx.x;
  const int grp = wg >> 6, slc = wg & 63;
  const int tid = threadIdx.x;
  const int wave = tid >> 6, lane = tid & 63;
  const int b0 = grp << 4, d0 = slc << 3;

  __shared__ float gbuf[4][16][33];
  __shared__ float bias_l[2][32];

  const int c15 = lane & 15, kg = lane >> 4;
  const int b = b0 + c15;

  bf16x8 wA[2][8], wB[2][8];
  load_weights(Wih, Whh, wave, c15, kg, d0, wA, wB);
  if (tid < 64) {
    const int l = tid >> 5, n = tid & 31;
    const int grow = (n >> 3) * DDIM + d0 + (n & 7);
    bias_l[l][n] = bih[l * 2048 + grow] + bhh[l * 2048 + grow];
  }
  if (tid < 128) {  // h_init -> slot1 (gen -1, tag 1)
    const int l = tid >> 6, r6 = tid & 63, rw = r6 >> 2, dp = r6 & 3;
    const int b2 = b0 + rw, dc = d0 + 2 * dp;
    const float2 hv = *(const float2*)&h_init[((size_t)l * NB + b2) * DDIM + dc];
    stg_tag(&hbuf[((size_t)(l * 2 + 1) * NB + b2) * DDIM + dc], hv.x, hv.y, 0x00010001u);
  }
  if (tid < 64) {  // y(-1)=initial -> slot1 (gen -1, tag 1)
    const int rw = tid >> 2, dp = tid & 3;
    const int dc = d0 + 2 * dp;
    stg_tag(&ybuf[((size_t)1 * NB + b0 + rw) * DDIM + dc], initial[dc], initial[dc + 1],
            0x00010001u);
  }
  const int rw0 = lane >> 2, dp0 = lane & 3;
  float cA0 = 0.f, cB0 = 0.f, cA1 = 0.f, cB1 = 0.f;
  if (wave == 0) {
    const float2 c0 = *(const float2*)&c_init[((size_t)0 * NB + b0 + rw0) * DDIM + d0 + 2 * dp0];
    const float2 c1 = *(const float2*)&c_init[((size_t)1 * NB + b0 + rw0) * DDIM + d0 + 2 * dp0];
    cA0 = c0.x; cB0 = c0.y; cA1 = c1.x; cB1 = c1.y;
  }
  __syncthreads();

  auto level = [&](auto lcc, const int t, const int p, const int rp) {
    constexpr int LC = decltype(lcc)::v;
    const unsigned patold = tagpat(t - 1);
    f32x4 pa0 = {0.f, 0.f, 0.f, 0.f}, pa1 = {0.f, 0.f, 0.f, 0.f};
    // -- pre-barrier: recurrent half h_LC(t-1) (tag-retry; covers init race) --
    if (wave >= 2) {
      const int kq = (wave - 2) << 8;
      FRAG f[8];
      const bf16_t* ap = hbuf + ((size_t)(LC * 2 + rp) * NB + b) * DDIM + kq + kg * 8;
      int guard = 0;
      for (;;) {
#pragma unroll
        for (int ks = 0; ks < 8; ++ks) ldg_issue(ap + ks * 32, f[ks].i);
        vm_wait0();
        unsigned bad = 0;
#pragma unroll
        for (int ks = 0; ks < 8; ++ks) bad |= chk4(f[ks].i, patold);
        if (__all(bad == 0) || ++guard > RETRY_CAP) break;
      }
#pragma unroll
      for (int ks = 0; ks < 8; ++ks) {
        pa0 = MFMA16(f[ks].v, wA[LC][ks], pa0);
        pa1 = MFMA16(f[ks].v, wB[LC][ks], pa1);
      }
    }
    __syncthreads();
    if (wave >= 2) {
#pragma unroll
      for (int r = 0; r < 4; ++r) {
        gbuf[wave][kg * 4 + r][c15] = pa0[r];
        gbuf[wave][kg * 4 + r][16 + c15] = pa1[r];
      }
    } else {  // fresh half: L0 reads y(t-1) [gen t-1]; L1 reads h0(t) [gen t]
      const int kq = wave << 8;
      const unsigned patf = (LC == 0) ? patold : tagpat(t);
      const bf16_t* base = (LC == 0) ? (ybuf + (size_t)rp * NB * DDIM)
                                     : (hbuf + (size_t)(0 * 2 + p) * NB * DDIM);
      const bf16_t* ap = base + (size_t)b * DDIM + kq + kg * 8;
      FRAG f[8];
      int guard = 0;
      for (;;) {
#pragma unroll
        for (int ks = 0; ks < 8; ++ks) ldg_issue(ap + ks * 32, f[ks].i);
        vm_wait0();
        unsigned bad = 0;
#pragma unroll
        for (int ks = 0; ks < 8; ++ks) bad |= chk4(f[ks].i, patf);
        if (__all(bad == 0) || ++guard > RETRY_CAP) break;
      }
      f32x4 a0 = {0.f, 0.f, 0.f, 0.f}, a1 = {0.f, 0.f, 0.f, 0.f};
#pragma unroll
      for (int ks = 0; ks < 8; ++ks) {
        a0 = MFMA16(f[ks].v, wA[LC][ks], a0);
        a1 = MFMA16(f[ks].v, wB[LC][ks], a1);
      }
#pragma unroll
      for (int r = 0; r < 4; ++r) {
        gbuf[wave][kg * 4 + r][c15] = a0[r];
        gbuf[wave][kg * 4 + r][16 + c15] = a1[r];
      }
    }
    __syncthreads();
    // -- epilogue (wave0): h/y stores carry tag(t) --
    if (tid < 64) {
      const unsigned pat = tagpat(t);
      float hv2[2];
#pragma unroll
      for (int e2 = 0; e2 < 2; ++e2) {
        const int e = dp0 * 2 + e2;
        float gi = bias_l[LC][e],      gf = bias_l[LC][8 + e];
        float gg = bias_l[LC][16 + e], go = bias_l[LC][24 + e];
#pragma unroll
        for (int q = 0; q < 4; ++q) {
          gi += gbuf[q][rw0][e];
          gf += gbuf[q][rw0][8 + e];
          gg += gbuf[q][rw0][16 + e];
          go += gbuf[q][rw0][24 + e];
        }
        const float iv = sigm_f(gi), fv = sigm_f(gf), gv = tanh_f(gg), ov = sigm_f(go);
        float& cs = (LC == 0) ? ((e2 == 0) ? cA0 : cB0) : ((e2 == 0) ? cA1 : cB1);
        cs = fv * cs + iv * gv;
        hv2[e2] = ov * tanh_f(cs);
      }
      const int b2 = b0 + rw0, dc = d0 + dp0 * 2;
      stg_tag(&hbuf[((size_t)(LC * 2 + p) * NB + b2) * DDIM + dc], hv2[0], hv2[1], pat);
      if (LC == 1) {
        stg_tag(&ybuf[((size_t)p * NB + b2) * DDIM + dc], hv2[0], hv2[1], pat);
        *(float2*)&out[((size_t)b2 * TSEQ + t) * DDIM + dc] = float2{hv2[0], hv2[1]};
      }
    }
  };

  for (int t = 0; t < TSEQ; ++t) {
    const int p = t & 1, rp = p ^ 1;
    level(IC<0>{}, t, p, rp);
    level(IC<1>{}, t, p, rp);
  }
}

__global__ __launch_bounds__(512) void vae_kernel(
    const float* __restrict__ hT, const float* __restrict__ cT,
    const float* __restrict__ hmuW, const float* __restrict__ hmub,
    const float* __restrict__ hsigW, const float* __restrict__ hsigb,
    const float* __restrict__ houtW, const float* __restrict__ houtb,
    const float* __restrict__ cmuW, const float* __restrict__ cmub,
    const float* __restrict__ csigW, const float* __restrict__ csigb,
    const float* __restrict__ coutW, const float* __restrict__ coutb,
    const float* __restrict__ eps_h, const float* __restrict__ eps_c,
    float* __restrict__ h2, float* __restrict__ c2, float* __restrict__ out) {
  const int bid = blockIdx.x;  // (hc, layer, b)
  const int b = bid & 63;
  const int l = (bid >> 6) & 1;
  const int hc = bid >> 7;
  const int tid = threadIdx.x;

  const float* S    = (hc ? cT : hT) + (l * 64 + b) * 512;
  const float* muW  = (hc ? cmuW : hmuW) + l * 64 * 512;
  const float* mub  = (hc ? cmub : hmub) + l * 64;
  const float* sigW = (hc ? csigW : hsigW) + l * 64 * 512;
  const float* sigb = (hc ? csigb : hsigb) + l * 64;
  const float* outW = (hc ? coutW : houtW) + l * 512 * 64;
  const float* outb = (hc ? coutb : houtb) + l * 512;
  const float* eps  = (hc ? eps_c : eps_h) + (l * 64 + b) * 64;
  float* S2 = (hc ? c2 : h2) + (l * 64 + b) * 512;

  __shared__ float srow[512];
  __shared__ float z[64];
  srow[tid] = S[tid];
  __syncthreads();
  if (tid < 64) {
    const float* wm = muW + tid * 512;
    const float* ws = sigW + tid * 512;
    float mu = mub[tid], sg = sigb[tid];
    for (int d = 0; d < 512; ++d) {
      mu = fmaf(srow[d], wm[d], mu);
      sg = fmaf(srow[d], ws[d], sg);
    }
    z[tid] = mu + eps[tid] * sg;
    const size_t base = (size_t)64 * 512 * 512;
    const size_t idx = ((size_t)(hc * 2 + l) * 64 + b) * 64 + tid;
    out[base + idx] = mu;
    out[base + 4 * 64 * 64 + idx] = sg;
  }
  __syncthreads();
  {
    const float* wo = outW + tid * 64;
    float acc = outb[tid];
#pragma unroll 8
    for (int g = 0; g < 64; ++g) acc = fmaf(z[g], wo[g], acc);
    S2[tid] = acc;
  }
}

extern "C" void kernel_launch(void* const* d_in, const int* in_sizes, int n_in,
                              void* d_out, int out_size, void* d_ws, size_t ws_size,
                              hipStream_t stream) {
  const float* x       = (const float*)d_in[0];
  const float* initial = (const float*)d_in[1];
  const float* eWih    = (const float*)d_in[2];
  const float* eWhh    = (const float*)d_in[3];
  const float* ebih    = (const float*)d_in[4];
  const float* ebhh    = (const float*)d_in[5];
  const float* dWih    = (const float*)d_in[6];
  const float* dWhh    = (const float*)d_in[7];
  const float* dbih    = (const float*)d_in[8];
  const float* dbhh    = (const float*)d_in[9];
  const float* hmuW    = (const float*)d_in[10];
  const float* hmub    = (const float*)d_in[11];
  const float* hsigW   = (const float*)d_in[12];
  const float* hsigb   = (const float*)d_in[13];
  const float* houtW   = (const float*)d_in[14];
  const float* houtb   = (const float*)d_in[15];
  const float* cmuW    = (const float*)d_in[16];
  const float* cmub    = (const float*)d_in[17];
  const float* csigW   = (const float*)d_in[18];
  const float* csigb   = (const float*)d_in[19];
  const float* coutW   = (const float*)d_in[20];
  const float* coutb   = (const float*)d_in[21];
  const float* eps_h   = (const float*)d_in[22];
  const float* eps_c   = (const float*)d_in[23];

  char* ws = (char*)d_ws;
  bf16_t* enc_hbuf = (bf16_t*)(ws + OFF_ENC_HBUF);
  bf16_t* dec_hbuf = (bf16_t*)(ws + OFF_DEC_HBUF);
  bf16_t* dec_ybuf = (bf16_t*)(ws + OFF_DEC_YBUF);
  float* hT = (float*)(ws + OFF_HT);
  float* cT = (float*)(ws + OFF_CT);
  float* h2 = (float*)(ws + OFF_H2);
  float* c2 = (float*)(ws + OFF_C2);
  unsigned* gx = (unsigned*)(ws + OFF_GX);
  float* out = (float*)d_out;

  // zero all exchange buffers every call: tag LSB of unwritten data must be 0
  hipMemsetAsync(ws, 0, OFF_HT, stream);

  const bool use_gx = (ws_size >= OFF_GX + GX_BYTES);
  if (use_gx) {
    gx_pass<<<2048, 256, 0, stream>>>(x, eWih, gx);
    enc_pass<1><<<256, 256, 0, stream>>>(x, eWih, eWhh, ebih, ebhh, enc_hbuf, hT, cT, gx);
  } else {
    enc_pass<0><<<256, 256, 0, stream>>>(x, eWih, eWhh, ebih, ebhh, enc_hbuf, hT, cT, nullptr);
  }
  vae_kernel<<<256, 512, 0, stream>>>(hT, cT, hmuW, hmub, hsigW, hsigb, houtW, houtb,
                                      cmuW, cmub, csigW, csigb, coutW, coutb,
                                      eps_h, eps_c, h2, c2, out);
  dec_pass<<<256, 256, 0, stream>>>(initial, dWih, dWhh, dbih, dbhh,
                                    h2, c2, dec_hbuf, dec_ybuf, out);
}

// Round 8
// 4890.587 us; speedup vs baseline: 3.8310x; 1.0055x over previous
//
#include <hip/hip_runtime.h>
#include <hip/hip_bf16.h>

typedef __bf16 bf16_t;
typedef __attribute__((ext_vector_type(8))) __bf16 bf16x8;
typedef __attribute__((ext_vector_type(4))) float f32x4;
typedef __attribute__((ext_vector_type(4))) int i32x4;

#define MFMA16(a, b, c) __builtin_amdgcn_mfma_f32_16x16x32_bf16((a), (b), (c), 0, 0, 0)

namespace {
constexpr int TSEQ = 512, DDIM = 512, NB = 64;
constexpr size_t OFF_ENC_HBUF = 0;        // bf16 [2 layer][2 slot][64][512]
constexpr size_t OFF_DEC_HBUF = 262144;   // bf16 [2][2][64][512]
constexpr size_t OFF_DEC_YBUF = 524288;   // bf16 [2 slot][64][512]
constexpr size_t OFF_HT       = 655360;   // f32 [2][64][512]
constexpr size_t OFF_CT       = 917504;
constexpr size_t OFF_H2       = 1179648;
constexpr size_t OFF_C2       = 1441792;
constexpr size_t OFF_GX       = 2097152;  // u32 [512 t][256 wg][256] fp16x2
constexpr size_t GX_BYTES     = (size_t)512 * 256 * 256 * 4;  // 134 MB
constexpr int RETRY_CAP = 1 << 14;  // bounded spin: bug -> wrong answer, never a hang
template <int V> struct IC { static constexpr int v = V; };
}  // namespace

__device__ __forceinline__ float sigm_f(float x) { return 1.f / (1.f + __expf(-x)); }
__device__ __forceinline__ float tanh_f(float x) {
  x = fminf(15.f, fmaxf(-15.f, x));
  const float e = __expf(-2.f * x);
  return (1.f - e) / (1.f + e);
}
__device__ __forceinline__ bf16x8 cvt8(const float* __restrict__ p) {
  const float4 a = *(const float4*)p;
  const float4 b = *(const float4*)(p + 4);
  bf16x8 r;
  r[0] = (bf16_t)a.x; r[1] = (bf16_t)a.y; r[2] = (bf16_t)a.z; r[3] = (bf16_t)a.w;
  r[4] = (bf16_t)b.x; r[5] = (bf16_t)b.y; r[6] = (bf16_t)b.z; r[7] = (bf16_t)b.w;
  return r;
}

union FRAG { i32x4 i; bf16x8 v; };

// generation tag in the LSB of each bf16: tag(g) != tag(g+2); tag of every
// FIRST write to a slot is 1 (!= zeroed/0xAA-poisoned memory whose LSB is 0)
__device__ __forceinline__ unsigned tagpat(int g) {  // g >= -1
  return ((((g + 1) >> 1) & 1) ^ 1) ? 0x00010001u : 0u;
}
__device__ __forceinline__ unsigned chk4(const i32x4& v, unsigned pat) {
  unsigned bad = 0;
#pragma unroll
  for (int j = 0; j < 4; ++j) bad |= ((unsigned)v[j] ^ pat) & 0x00010001u;
  return bad;
}

// L1/L2-bypassing ops through L3 (the cross-XCD coherence point) — R2/R4/R6-proven
__device__ __forceinline__ void ldg_issue(const bf16_t* p, i32x4& d) {
  asm volatile("global_load_dwordx4 %0, %1, off sc0 sc1" : "=v"(d) : "v"(p) : "memory");
}
__device__ __forceinline__ void vm_wait0() {
  asm volatile("s_waitcnt vmcnt(0)" ::: "memory");
  __builtin_amdgcn_sched_barrier(0);  // keep tag-check / MFMA below the wait
}
__device__ __forceinline__ void stg_tag(bf16_t* p, float a, float b, unsigned pat) {
  union { bf16_t h[2]; unsigned u; } x;
  x.h[0] = (bf16_t)a; x.h[1] = (bf16_t)b;
  __hip_atomic_store((unsigned*)p, (x.u & ~0x00010001u) | pat,
                     __ATOMIC_RELAXED, __HIP_MEMORY_SCOPE_AGENT);
}

__device__ __forceinline__ void load_weights(const float* Wih, const float* Whh,
                                             int wave, int c15, int kg, int d0,
                                             bf16x8 (&wA)[2][8], bf16x8 (&wB)[2][8]) {
  const float* Wsrc = (wave < 2) ? Wih : Whh;
  const int kb = (wave & 1) << 8;
#pragma unroll
  for (int l = 0; l < 2; ++l)
#pragma unroll
    for (int nt = 0; nt < 2; ++nt)
#pragma unroll
      for (int ks = 0; ks < 8; ++ks) {
        const int n = nt * 16 + c15;
        const int grow = (n >> 3) * DDIM + d0 + (n & 7);
        const float* p = Wsrc + (size_t)(l * 2048 + grow) * DDIM + kb + ks * 32 + kg * 8;
        if (nt == 0) wA[l][ks] = cvt8(p);
        else         wB[l][ks] = cvt8(p);
      }
}

// ---------------- pre-pass: gx[t] = x_t @ Wih0^T (fp16), fully parallel ----------------
__global__ __launch_bounds__(256, 4) void gx_pass(
    const float* __restrict__ x, const float* __restrict__ Wih,
    unsigned* __restrict__ gx) {
  const int wg0 = blockIdx.x & 255;   // same (grp,slc) mapping as enc_pass
  const int tc  = blockIdx.x >> 8;    // 0..7, 64 timesteps each
  const int grp = wg0 >> 6, slc = wg0 & 63;
  const int tid = threadIdx.x;
  const int wave = tid >> 6, lane = tid & 63;
  const int c15 = lane & 15, kg = lane >> 4;
  const int b0 = grp << 4, d0 = slc << 3;
  const int kb = (wave & 1) << 8;   // K-half, exactly like enc x-path
  const int tpar = wave >> 1;       // waves 0-1 -> even t, 2-3 -> odd t

  __shared__ float gbuf[2][2][16][33];

  bf16x8 wA[8], wB[8];  // layer-0 Wih fragments only
#pragma unroll
  for (int nt = 0; nt < 2; ++nt)
#pragma unroll
    for (int ks = 0; ks < 8; ++ks) {
      const int n = nt * 16 + c15;
      const int grow = (n >> 3) * DDIM + d0 + (n & 7);
      const float* p = Wih + (size_t)grow * DDIM + kb + ks * 32 + kg * 8;
      if (nt == 0) wA[ks] = cvt8(p);
      else         wB[ks] = cvt8(p);
    }

  const int b = b0 + c15;
  for (int j = 0; j < 32; ++j) {
    const int t = tc * 64 + 2 * j + tpar;
    f32x4 a0 = {0.f, 0.f, 0.f, 0.f}, a1 = {0.f, 0.f, 0.f, 0.f};
    const float* ap = x + ((size_t)b * TSEQ + t) * DDIM + kb + kg * 8;
#pragma unroll
    for (int ks = 0; ks < 8; ++ks) {
      const bf16x8 a = cvt8(ap + ks * 32);  // identical convert path to R4 enc
      a0 = MFMA16(a, wA[ks], a0);
      a1 = MFMA16(a, wB[ks], a1);
    }
#pragma unroll
    for (int r = 0; r < 4; ++r) {
      gbuf[tpar][wave & 1][kg * 4 + r][c15] = a0[r];
      gbuf[tpar][wave & 1][kg * 4 + r][16 + c15] = a1[r];
    }
    __syncthreads();
    if (tid < 128) {
      const int ll = tid >> 6, r6 = tid & 63, rw = r6 >> 2, dp = r6 & 3;
      const int tt = tc * 64 + 2 * j + ll;
      const size_t base = ((size_t)tt * 256 + wg0) * 256 + rw * 16 + dp;
#pragma unroll
      for (int g = 0; g < 4; ++g) {
        const int e = g * 8 + 2 * dp;
        const float v0 = gbuf[ll][0][rw][e] + gbuf[ll][1][rw][e];
        const float v1 = gbuf[ll][0][rw][e + 1] + gbuf[ll][1][rw][e + 1];
        union { _Float16 h[2]; unsigned u; } pk;
        pk.h[0] = (_Float16)v0; pk.h[1] = (_Float16)v1;
        __builtin_nontemporal_store(pk.u, &gx[base + g * 4]);  // write-once: keep out of L3
      }
    }
    __syncthreads();
  }
}

// ---------------- encoder: diagonal wavefront; GX=1 reads precomputed x-half ----------------
template <int GX>
__global__ __launch_bounds__(256, 1) void enc_pass(
    const float* __restrict__ x,
    const float* __restrict__ Wih, const float* __restrict__ Whh,
    const float* __restrict__ bih, const float* __restrict__ bhh,
    bf16_t* __restrict__ hbuf, float* __restrict__ hT, float* __restrict__ cT,
    const unsigned* __restrict__ gx) {
  const int wg = blockIdx.x;
  const int grp = wg >> 6, slc = wg & 63;
  const int tid = threadIdx.x;
  const int wave = tid >> 6, lane = tid & 63;
  const int b0 = grp << 4, d0 = slc << 3;

  __shared__ float gbuf[2][4][16][33];
  __shared__ float bias_l[2][32];

  const int c15 = lane & 15, kg = lane >> 4;
  const int b = b0 + c15;

  bf16x8 wA[2][8], wB[2][8];
  load_weights(Wih, Whh, wave, c15, kg, d0, wA, wB);
  if (tid < 64) {
    const int l = tid >> 5, n = tid & 31;
    const int grow = (n >> 3) * DDIM + d0 + (n & 7);
    bias_l[l][n] = bih[l * 2048 + grow] + bhh[l * 2048 + grow];
  }
  if (tid < 128) {  // h0(-1)=0 -> slot1 (gen -1); h1(-1)=0 -> slot0 (gen 0); both tag=1
    const int l = tid >> 6, r6 = tid & 63, rw = r6 >> 2, dp = r6 & 3;
    const int slot = (l == 0) ? 1 : 0;
    stg_tag(&hbuf[((size_t)(l * 2 + slot) * NB + b0 + rw) * DDIM + d0 + 2 * dp],
            0.f, 0.f, 0x00010001u);
  }
  __syncthreads();

  float cA = 0.f, cB = 0.f;  // wave0: L0 c-state pair; wave1: L1 c-state pair

  for (int s = 0; s <= TSEQ; ++s) {
    const int p = s & 1, rp = p ^ 1;
    const unsigned patold = tagpat(s - 1);
    // -- pre-barrier: L0 x-half --
    f32x4 pa0 = {0.f, 0.f, 0.f, 0.f}, pa1 = {0.f, 0.f, 0.f, 0.f};
    unsigned gxr[4];
    if constexpr (GX) {
      if (tid < 64 && s < TSEQ) {  // 4 nt loads (read-once stream, keep out of L3)
        const size_t base = ((size_t)s * 256 + wg) * 256 + (tid >> 2) * 16 + (tid & 3);
#pragma unroll
        for (int g = 0; g < 4; ++g) gxr[g] = __builtin_nontemporal_load(&gx[base + g * 4]);
      }
    } else {
      if (wave < 2 && s < TSEQ) {
        const int kq = wave << 8;
        const float* ap = x + ((size_t)b * TSEQ + s) * DDIM + kq + kg * 8;
#pragma unroll
        for (int ks = 0; ks < 8; ++ks) {
          const bf16x8 a = cvt8(ap + ks * 32);
          pa0 = MFMA16(a, wA[0][ks], pa0);
          pa1 = MFMA16(a, wB[0][ks], pa1);
        }
      }
    }
    __syncthreads();
    if (wave >= 2) {  // L0-recurrent (h0(s-1)) + L1-recurrent (h1(s-1)), tag-retry
      const int kq = (wave - 2) << 8;
      FRAG f0[8], f1[8];
      const bf16_t* a0p = hbuf + ((size_t)(0 * 2 + rp) * NB + b) * DDIM + kq + kg * 8;
      const bf16_t* a1p = hbuf + ((size_t)(1 * 2 + rp) * NB + b) * DDIM + kq + kg * 8;
      int guard = 0;
      for (;;) {
        if (s < TSEQ) {
#pragma unroll
          for (int ks = 0; ks < 8; ++ks) ldg_issue(a0p + ks * 32, f0[ks].i);
        }
        if (s >= 1) {
#pragma unroll
          for (int ks = 0; ks < 8; ++ks) ldg_issue(a1p + ks * 32, f1[ks].i);
        }
        vm_wait0();
        unsigned bad = 0;
        if (s < TSEQ) {
#pragma unroll
          for (int ks = 0; ks < 8; ++ks) bad |= chk4(f0[ks].i, patold);
        }
        if (s >= 1) {
#pragma unroll
          for (int ks = 0; ks < 8; ++ks) bad |= chk4(f1[ks].i, patold);
        }
        if (__all(bad == 0) || ++guard > RETRY_CAP) break;
      }
      if (s < TSEQ) {
        f32x4 a0 = {0.f, 0.f, 0.f, 0.f}, a1 = {0.f, 0.f, 0.f, 0.f};
#pragma unroll
        for (int ks = 0; ks < 8; ++ks) {
          a0 = MFMA16(f0[ks].v, wA[0][ks], a0);
          a1 = MFMA16(f0[ks].v, wB[0][ks], a1);
        }
#pragma unroll
        for (int r = 0; r < 4; ++r) {
          gbuf[0][wave][kg * 4 + r][c15] = a0[r];
          gbuf[0][wave][kg * 4 + r][16 + c15] = a1[r];
        }
      }
      if (s >= 1) {
        f32x4 a0 = {0.f, 0.f, 0.f, 0.f}, a1 = {0.f, 0.f, 0.f, 0.f};
#pragma unroll
        for (int ks = 0; ks < 8; ++ks) {
          a0 = MFMA16(f1[ks].v, wA[1][ks], a0);
          a1 = MFMA16(f1[ks].v, wB[1][ks], a1);
        }
#pragma unroll
        for (int r = 0; r < 4; ++r) {
          gbuf[1][wave][kg * 4 + r][c15] = a0[r];
          gbuf[1][wave][kg * 4 + r][16 + c15] = a1[r];
        }
      }
    } else {
      if constexpr (!GX) {
        if (s < TSEQ) {  // commit x-half accumulators (post-barrier: race-safe)
#pragma unroll
          for (int r = 0; r < 4; ++r) {
            gbuf[0][wave][kg * 4 + r][c15] = pa0[r];
            gbuf[0][wave][kg * 4 + r][16 + c15] = pa1[r];
          }
        }
      }
      if (s >= 1) {  // L1 input half: A = h0(s-1), tag-retry
        const int kq = wave << 8;
        FRAG f[8];
        const bf16_t* ap = hbuf + ((size_t)(0 * 2 + rp) * NB + b) * DDIM + kq + kg * 8;
        int guard = 0;
        for (;;) {
#pragma unroll
          for (int ks = 0; ks < 8; ++ks) ldg_issue(ap + ks * 32, f[ks].i);
          vm_wait0();
          unsigned bad = 0;
#pragma unroll
          for (int ks = 0; ks < 8; ++ks) bad |= chk4(f[ks].i, patold);
          if (__all(bad == 0) || ++guard > RETRY_CAP) break;
        }
        f32x4 a0 = {0.f, 0.f, 0.f, 0.f}, a1 = {0.f, 0.f, 0.f, 0.f};
#pragma unroll
        for (int ks = 0; ks < 8; ++ks) {
          a0 = MFMA16(f[ks].v, wA[1][ks], a0);
          a1 = MFMA16(f[ks].v, wB[1][ks], a1);
        }
#pragma unroll
        for (int r = 0; r < 4; ++r) {
          gbuf[1][wave][kg * 4 + r][c15] = a0[r];
          gbuf[1][wave][kg * 4 + r][16 + c15] = a1[r];
        }
      }
    }
    __syncthreads();
    // -- epilogue: wave0 -> L0, wave1 -> L1; stores carry tag(s) --
    if (tid < 128) {
      const int ll = tid >> 6, r6 = tid & 63, rw = r6 >> 2, dp = r6 & 3;
      const bool act = (ll == 0) ? (s < TSEQ) : (s >= 1);
      if (act) {
        const unsigned pat = tagpat(s);
        float gs[4][2];
#pragma unroll
        for (int g = 0; g < 4; ++g) {
          gs[g][0] = bias_l[ll][g * 8 + 2 * dp];
          gs[g][1] = bias_l[ll][g * 8 + 2 * dp + 1];
        }
        if (GX && ll == 0) {
#pragma unroll
          for (int g = 0; g < 4; ++g) {
            union { unsigned u; _Float16 h[2]; } dk;
            dk.u = gxr[g];
            gs[g][0] += (float)dk.h[0];
            gs[g][1] += (float)dk.h[1];
          }
        }
        const int q0 = (GX && ll == 0) ? 2 : 0;
#pragma unroll
        for (int q = 0; q < 4; ++q) {
          if (q >= q0) {
#pragma unroll
            for (int g = 0; g < 4; ++g) {
              const int e = g * 8 + 2 * dp;
              gs[g][0] += gbuf[ll][q][rw][e];
              gs[g][1] += gbuf[ll][q][rw][e + 1];
            }
          }
        }
        float hv2[2], cv2[2];
#pragma unroll
        for (int e2 = 0; e2 < 2; ++e2) {
          const float iv = sigm_f(gs[0][e2]), fv = sigm_f(gs[1][e2]);
          const float gv = tanh_f(gs[2][e2]), ov = sigm_f(gs[3][e2]);
          float& cs = (e2 == 0) ? cA : cB;
          cs = fv * cs + iv * gv;
          cv2[e2] = cs;
          hv2[e2] = ov * tanh_f(cs);
        }
        const int b2 = b0 + rw, dc = d0 + dp * 2;
        stg_tag(&hbuf[((size_t)(ll * 2 + p) * NB + b2) * DDIM + dc], hv2[0], hv2[1], pat);
        if ((ll == 0 && s == TSEQ - 1) || (ll == 1 && s == TSEQ)) {
          *(float2*)&hT[((size_t)ll * NB + b2) * DDIM + dc] = float2{hv2[0], hv2[1]};
          *(float2*)&cT[((size_t)ll * NB + b2) * DDIM + dc] = float2{cv2[0], cv2[1]};
        }
      }
    }
  }
}

// ---------------- decoder: serial chain, 1024 levels (R4/R6-proven + nt out) ----------------
__global__ __launch_bounds__(256, 1) void dec_pass(
    const float* __restrict__ initial,
    const float* __restrict__ Wih, const float* __restrict__ Whh,
    const float* __restrict__ bih, const float* __restrict__ bhh,
    const float* __restrict__ h_init, const float* __restrict__ c_init,
    bf16_t* __restrict__ hbuf, bf16_t* __restrict__ ybuf,
    float* __restrict__ out) {
  const int wg = blockIdx.x;
  const int grp = wg >> 6, slc = wg & 63;
  const int tid = threadIdx.x;
  const int wave = tid >> 6, lane = tid & 63;
  const int b0 = grp << 4, d0 = slc << 3;

  __shared__ float gbuf[4][16][33];
  __shared__ float bias_l[2][32];

  const int c15 = lane & 15, kg = lane >> 4;
  const int b = b0 + c15;

  bf16x8 wA[2][8], wB[2][8];
  load_weights(Wih, Whh, wave, c15, kg, d0, wA, wB);
  if (tid < 64) {
    const int l = tid >> 5, n = tid & 31;
    const int grow = (n >> 3) * DDIM + d0 + (n & 7);
    bias_l[l][n] = bih[l * 2048 + grow] + bhh[l * 2048 + grow];
  }
  if (tid < 128) {  // h_init -> slot1 (gen -1, tag 1)
    const int l = tid >> 6, r6 = tid & 63, rw = r6 >> 2, dp = r6 & 3;
    const int b2 = b0 + rw, dc = d0 + 2 * dp;
    const float2 hv = *(const float2*)&h_init[((size_t)l * NB + b2) * DDIM + dc];
    stg_tag(&hbuf[((size_t)(l * 2 + 1) * NB + b2) * DDIM + dc], hv.x, hv.y, 0x00010001u);
  }
  if (tid < 64) {  // y(-1)=initial -> slot1 (gen -1, tag 1)
    const int rw = tid >> 2, dp = tid & 3;
    const int dc = d0 + 2 * dp;
    stg_tag(&ybuf[((size_t)1 * NB + b0 + rw) * DDIM + dc], initial[dc], initial[dc + 1],
            0x00010001u);
  }
  const int rw0 = lane >> 2, dp0 = lane & 3;
  float cA0 = 0.f, cB0 = 0.f, cA1 = 0.f, cB1 = 0.f;
  if (wave == 0) {
    const float2 c0 = *(const float2*)&c_init[((size_t)0 * NB + b0 + rw0) * DDIM + d0 + 2 * dp0];
    const float2 c1 = *(const float2*)&c_init[((size_t)1 * NB + b0 + rw0) * DDIM + d0 + 2 * dp0];
    cA0 = c0.x; cB0 = c0.y; cA1 = c1.x; cB1 = c1.y;
  }
  __syncthreads();

  auto level = [&](auto lcc, const int t, const int p, const int rp) {
    constexpr int LC = decltype(lcc)::v;
    const unsigned patold = tagpat(t - 1);
    f32x4 pa0 = {0.f, 0.f, 0.f, 0.f}, pa1 = {0.f, 0.f, 0.f, 0.f};
    // -- pre-barrier: recurrent half h_LC(t-1) (tag-retry; covers init race) --
    if (wave >= 2) {
      const int kq = (wave - 2) << 8;
      FRAG f[8];
      const bf16_t* ap = hbuf + ((size_t)(LC * 2 + rp) * NB + b) * DDIM + kq + kg * 8;
      int guard = 0;
      for (;;) {
#pragma unroll
        for (int ks = 0; ks < 8; ++ks) ldg_issue(ap + ks * 32, f[ks].i);
        vm_wait0();
        unsigned bad = 0;
#pragma unroll
        for (int ks = 0; ks < 8; ++ks) bad |= chk4(f[ks].i, patold);
        if (__all(bad == 0) || ++guard > RETRY_CAP) break;
      }
#pragma unroll
      for (int ks = 0; ks < 8; ++ks) {
        pa0 = MFMA16(f[ks].v, wA[LC][ks], pa0);
        pa1 = MFMA16(f[ks].v, wB[LC][ks], pa1);
      }
    }
    __syncthreads();
    if (wave >= 2) {
#pragma unroll
      for (int r = 0; r < 4; ++r) {
        gbuf[wave][kg * 4 + r][c15] = pa0[r];
        gbuf[wave][kg * 4 + r][16 + c15] = pa1[r];
      }
    } else {  // fresh half: L0 reads y(t-1) [gen t-1]; L1 reads h0(t) [gen t]
      const int kq = wave << 8;
      const unsigned patf = (LC == 0) ? patold : tagpat(t);
      const bf16_t* base = (LC == 0) ? (ybuf + (size_t)rp * NB * DDIM)
                                     : (hbuf + (size_t)(0 * 2 + p) * NB * DDIM);
      const bf16_t* ap = base + (size_t)b * DDIM + kq + kg * 8;
      FRAG f[8];
      int guard = 0;
      for (;;) {
#pragma unroll
        for (int ks = 0; ks < 8; ++ks) ldg_issue(ap + ks * 32, f[ks].i);
        vm_wait0();
        unsigned bad = 0;
#pragma unroll
        for (int ks = 0; ks < 8; ++ks) bad |= chk4(f[ks].i, patf);
        if (__all(bad == 0) || ++guard > RETRY_CAP) break;
      }
      f32x4 a0 = {0.f, 0.f, 0.f, 0.f}, a1 = {0.f, 0.f, 0.f, 0.f};
#pragma unroll
      for (int ks = 0; ks < 8; ++ks) {
        a0 = MFMA16(f[ks].v, wA[LC][ks], a0);
        a1 = MFMA16(f[ks].v, wB[LC][ks], a1);
      }
#pragma unroll
      for (int r = 0; r < 4; ++r) {
        gbuf[wave][kg * 4 + r][c15] = a0[r];
        gbuf[wave][kg * 4 + r][16 + c15] = a1[r];
      }
    }
    __syncthreads();
    // -- epilogue (wave0): h/y stores carry tag(t) --
    if (tid < 64) {
      const unsigned pat = tagpat(t);
      float hv2[2];
#pragma unroll
      for (int e2 = 0; e2 < 2; ++e2) {
        const int e = dp0 * 2 + e2;
        float gi = bias_l[LC][e],      gf = bias_l[LC][8 + e];
        float gg = bias_l[LC][16 + e], go = bias_l[LC][24 + e];
#pragma unroll
        for (int q = 0; q < 4; ++q) {
          gi += gbuf[q][rw0][e];
          gf += gbuf[q][rw0][8 + e];
          gg += gbuf[q][rw0][16 + e];
          go += gbuf[q][rw0][24 + e];
        }
        const float iv = sigm_f(gi), fv = sigm_f(gf), gv = tanh_f(gg), ov = sigm_f(go);
        float& cs = (LC == 0) ? ((e2 == 0) ? cA0 : cB0) : ((e2 == 0) ? cA1 : cB1);
        cs = fv * cs + iv * gv;
        hv2[e2] = ov * tanh_f(cs);
      }
      const int b2 = b0 + rw0, dc = d0 + dp0 * 2;
      stg_tag(&hbuf[((size_t)(LC * 2 + p) * NB + b2) * DDIM + dc], hv2[0], hv2[1], pat);
      if (LC == 1) {
        stg_tag(&ybuf[((size_t)p * NB + b2) * DDIM + dc], hv2[0], hv2[1], pat);
        union { float f[2]; unsigned long long u; } ov;
        ov.f[0] = hv2[0]; ov.f[1] = hv2[1];  // nt: out is a write-once stream, keep L3 hot
        __builtin_nontemporal_store(ov.u, (unsigned long long*)&out[((size_t)b2 * TSEQ + t) * DDIM + dc]);
      }
    }
  };

  for (int t = 0; t < TSEQ; ++t) {
    const int p = t & 1, rp = p ^ 1;
    level(IC<0>{}, t, p, rp);
    level(IC<1>{}, t, p, rp);
  }
}

__global__ __launch_bounds__(512) void vae_kernel(
    const float* __restrict__ hT, const float* __restrict__ cT,
    const float* __restrict__ hmuW, const float* __restrict__ hmub,
    const float* __restrict__ hsigW, const float* __restrict__ hsigb,
    const float* __restrict__ houtW, const float* __restrict__ houtb,
    const float* __restrict__ cmuW, const float* __restrict__ cmub,
    const float* __restrict__ csigW, const float* __restrict__ csigb,
    const float* __restrict__ coutW, const float* __restrict__ coutb,
    const float* __restrict__ eps_h, const float* __restrict__ eps_c,
    float* __restrict__ h2, float* __restrict__ c2, float* __restrict__ out) {
  const int bid = blockIdx.x;  // (hc, layer, b)
  const int b = bid & 63;
  const int l = (bid >> 6) & 1;
  const int hc = bid >> 7;
  const int tid = threadIdx.x;

  const float* S    = (hc ? cT : hT) + (l * 64 + b) * 512;
  const float* muW  = (hc ? cmuW : hmuW) + l * 64 * 512;
  const float* mub  = (hc ? cmub : hmub) + l * 64;
  const float* sigW = (hc ? csigW : hsigW) + l * 64 * 512;
  const float* sigb = (hc ? csigb : hsigb) + l * 64;
  const float* outW = (hc ? coutW : houtW) + l * 512 * 64;
  const float* outb = (hc ? coutb : houtb) + l * 512;
  const float* eps  = (hc ? eps_c : eps_h) + (l * 64 + b) * 64;
  float* S2 = (hc ? c2 : h2) + (l * 64 + b) * 512;

  __shared__ float srow[512];
  __shared__ float z[64];
  srow[tid] = S[tid];
  __syncthreads();
  if (tid < 64) {
    const float* wm = muW + tid * 512;
    const float* ws = sigW + tid * 512;
    float mu = mub[tid], sg = sigb[tid];
    for (int d = 0; d < 512; ++d) {
      mu = fmaf(srow[d], wm[d], mu);
      sg = fmaf(srow[d], ws[d], sg);
    }
    z[tid] = mu + eps[tid] * sg;
    const size_t base = (size_t)64 * 512 * 512;
    const size_t idx = ((size_t)(hc * 2 + l) * 64 + b) * 64 + tid;
    out[base + idx] = mu;
    out[base + 4 * 64 * 64 + idx] = sg;
  }
  __syncthreads();
  {
    const float* wo = outW + tid * 64;
    float acc = outb[tid];
#pragma unroll 8
    for (int g = 0; g < 64; ++g) acc = fmaf(z[g], wo[g], acc);
    S2[tid] = acc;
  }
}

extern "C" void kernel_launch(void* const* d_in, const int* in_sizes, int n_in,
                              void* d_out, int out_size, void* d_ws, size_t ws_size,
                              hipStream_t stream) {
  const float* x       = (const float*)d_in[0];
  const float* initial = (const float*)d_in[1];
  const float* eWih    = (const float*)d_in[2];
  const float* eWhh    = (const float*)d_in[3];
  const float* ebih    = (const float*)d_in[4];
  const float* ebhh    = (const float*)d_in[5];
  const float* dWih    = (const float*)d_in[6];
  const float* dWhh    = (const float*)d_in[7];
  const float* dbih    = (const float*)d_in[8];
  const float* dbhh    = (const float*)d_in[9];
  const float* hmuW    = (const float*)d_in[10];
  const float* hmub    = (const float*)d_in[11];
  const float* hsigW   = (const float*)d_in[12];
  const float* hsigb   = (const float*)d_in[13];
  const float* houtW   = (const float*)d_in[14];
  const float* houtb   = (const float*)d_in[15];
  const float* cmuW    = (const float*)d_in[16];
  const float* cmub    = (const float*)d_in[17];
  const float* csigW   = (const float*)d_in[18];
  const float* csigb   = (const float*)d_in[19];
  const float* coutW   = (const float*)d_in[20];
  const float* coutb   = (const float*)d_in[21];
  const float* eps_h   = (const float*)d_in[22];
  const float* eps_c   = (const float*)d_in[23];

  char* ws = (char*)d_ws;
  bf16_t* enc_hbuf = (bf16_t*)(ws + OFF_ENC_HBUF);
  bf16_t* dec_hbuf = (bf16_t*)(ws + OFF_DEC_HBUF);
  bf16_t* dec_ybuf = (bf16_t*)(ws + OFF_DEC_YBUF);
  float* hT = (float*)(ws + OFF_HT);
  float* cT = (float*)(ws + OFF_CT);
  float* h2 = (float*)(ws + OFF_H2);
  float* c2 = (float*)(ws + OFF_C2);
  unsigned* gx = (unsigned*)(ws + OFF_GX);
  float* out = (float*)d_out;

  // zero all exchange buffers every call: tag LSB of unwritten data must be 0
  hipMemsetAsync(ws, 0, OFF_HT, stream);

  const bool use_gx = (ws_size >= OFF_GX + GX_BYTES);
  if (use_gx) {
    gx_pass<<<2048, 256, 0, stream>>>(x, eWih, gx);
    enc_pass<1><<<256, 256, 0, stream>>>(x, eWih, eWhh, ebih, ebhh, enc_hbuf, hT, cT, gx);
  } else {
    enc_pass<0><<<256, 256, 0, stream>>>(x, eWih, eWhh, ebih, ebhh, enc_hbuf, hT, cT, nullptr);
  }
  vae_kernel<<<256, 512, 0, stream>>>(hT, cT, hmuW, hmub, hsigW, hsigb, houtW, houtb,
                                      cmuW, cmub, csigW, csigb, coutW, coutb,
                                      eps_h, eps_c, h2, c2, out);
  dec_pass<<<256, 256, 0, stream>>>(initial, dWih, dWhh, dbih, dbhh,
                                    h2, c2, dec_hbuf, dec_ybuf, out);
}

// Round 9
// 4890.080 us; speedup vs baseline: 3.8314x; 1.0001x over previous
//
#include <hip/hip_runtime.h>
#include <hip/hip_bf16.h>

typedef __bf16 bf16_t;
typedef __attribute__((ext_vector_type(8))) __bf16 bf16x8;
typedef __attribute__((ext_vector_type(4))) float f32x4;
typedef __attribute__((ext_vector_type(4))) int i32x4;

#define MFMA16(a, b, c) __builtin_amdgcn_mfma_f32_16x16x32_bf16((a), (b), (c), 0, 0, 0)

namespace {
constexpr int TSEQ = 512, DDIM = 512, NB = 64;
constexpr size_t OFF_ENC_HBUF = 0;        // bf16 [2 layer][2 slot][64][512]
constexpr size_t OFF_DEC_HBUF = 262144;   // bf16 [2][2][64][512]
constexpr size_t OFF_DEC_YBUF = 524288;   // bf16 [2 slot][64][512]
constexpr size_t OFF_HT       = 655360;   // f32 [2][64][512]
constexpr size_t OFF_CT       = 917504;
constexpr size_t OFF_H2       = 1179648;
constexpr size_t OFF_C2       = 1441792;
constexpr size_t OFF_GX       = 2097152;  // u32 [512 t][256 wg][256] fp16x2
constexpr size_t GX_BYTES     = (size_t)512 * 256 * 256 * 4;  // 134 MB
constexpr int RETRY_CAP = 1 << 14;  // bounded spin: bug -> wrong answer, never a hang
template <int V> struct IC { static constexpr int v = V; };
}  // namespace

__device__ __forceinline__ float sigm_f(float x) { return 1.f / (1.f + __expf(-x)); }
__device__ __forceinline__ float tanh_f(float x) {
  x = fminf(15.f, fmaxf(-15.f, x));
  const float e = __expf(-2.f * x);
  return (1.f - e) / (1.f + e);
}
__device__ __forceinline__ bf16x8 cvt8(const float* __restrict__ p) {
  const float4 a = *(const float4*)p;
  const float4 b = *(const float4*)(p + 4);
  bf16x8 r;
  r[0] = (bf16_t)a.x; r[1] = (bf16_t)a.y; r[2] = (bf16_t)a.z; r[3] = (bf16_t)a.w;
  r[4] = (bf16_t)b.x; r[5] = (bf16_t)b.y; r[6] = (bf16_t)b.z; r[7] = (bf16_t)b.w;
  return r;
}

union FRAG { i32x4 i; bf16x8 v; };

// generation tag in the LSB of each bf16: tag(g) != tag(g+2); tag of every
// FIRST write to a slot is 1 (!= zeroed/0xAA-poisoned memory whose LSB is 0)
__device__ __forceinline__ unsigned tagpat(int g) {  // g >= -1
  return ((((g + 1) >> 1) & 1) ^ 1) ? 0x00010001u : 0u;
}
__device__ __forceinline__ unsigned chk4(const i32x4& v, unsigned pat) {
  unsigned bad = 0;
#pragma unroll
  for (int j = 0; j < 4; ++j) bad |= ((unsigned)v[j] ^ pat) & 0x00010001u;
  return bad;
}

// DEVICE-scope load (sc1 only): bypasses L1 + non-coherent per-XCD L2, but is
// SERVED BY the shared L3 (Infinity Cache) — the cross-XCD coherence point.
// R2..R8 used `sc0 sc1` = SYSTEM scope, which also bypasses L3 -> every poll
// paid a full HBM round-trip (the ~450 MB FETCH_SIZE signature).
__device__ __forceinline__ void ldg_issue(const bf16_t* p, i32x4& d) {
  asm volatile("global_load_dwordx4 %0, %1, off sc1" : "=v"(d) : "v"(p) : "memory");
}
__device__ __forceinline__ void vm_wait0() {
  asm volatile("s_waitcnt vmcnt(0)" ::: "memory");
  __builtin_amdgcn_sched_barrier(0);  // keep tag-check / MFMA below the wait
}
__device__ __forceinline__ void stg_tag(bf16_t* p, float a, float b, unsigned pat) {
  union { bf16_t h[2]; unsigned u; } x;
  x.h[0] = (bf16_t)a; x.h[1] = (bf16_t)b;
  __hip_atomic_store((unsigned*)p, (x.u & ~0x00010001u) | pat,
                     __ATOMIC_RELAXED, __HIP_MEMORY_SCOPE_AGENT);
}

__device__ __forceinline__ void load_weights(const float* Wih, const float* Whh,
                                             int wave, int c15, int kg, int d0,
                                             bf16x8 (&wA)[2][8], bf16x8 (&wB)[2][8]) {
  const float* Wsrc = (wave < 2) ? Wih : Whh;
  const int kb = (wave & 1) << 8;
#pragma unroll
  for (int l = 0; l < 2; ++l)
#pragma unroll
    for (int nt = 0; nt < 2; ++nt)
#pragma unroll
      for (int ks = 0; ks < 8; ++ks) {
        const int n = nt * 16 + c15;
        const int grow = (n >> 3) * DDIM + d0 + (n & 7);
        const float* p = Wsrc + (size_t)(l * 2048 + grow) * DDIM + kb + ks * 32 + kg * 8;
        if (nt == 0) wA[l][ks] = cvt8(p);
        else         wB[l][ks] = cvt8(p);
      }
}

// ---------------- pre-pass: gx[t] = x_t @ Wih0^T (fp16), fully parallel ----------------
__global__ __launch_bounds__(256, 4) void gx_pass(
    const float* __restrict__ x, const float* __restrict__ Wih,
    unsigned* __restrict__ gx) {
  const int wg0 = blockIdx.x & 255;   // same (grp,slc) mapping as enc_pass
  const int tc  = blockIdx.x >> 8;    // 0..7, 64 timesteps each
  const int grp = wg0 >> 6, slc = wg0 & 63;
  const int tid = threadIdx.x;
  const int wave = tid >> 6, lane = tid & 63;
  const int c15 = lane & 15, kg = lane >> 4;
  const int b0 = grp << 4, d0 = slc << 3;
  const int kb = (wave & 1) << 8;   // K-half, exactly like enc x-path
  const int tpar = wave >> 1;       // waves 0-1 -> even t, 2-3 -> odd t

  __shared__ float gbuf[2][2][16][33];

  bf16x8 wA[8], wB[8];  // layer-0 Wih fragments only
#pragma unroll
  for (int nt = 0; nt < 2; ++nt)
#pragma unroll
    for (int ks = 0; ks < 8; ++ks) {
      const int n = nt * 16 + c15;
      const int grow = (n >> 3) * DDIM + d0 + (n & 7);
      const float* p = Wih + (size_t)grow * DDIM + kb + ks * 32 + kg * 8;
      if (nt == 0) wA[ks] = cvt8(p);
      else         wB[ks] = cvt8(p);
    }

  const int b = b0 + c15;
  for (int j = 0; j < 32; ++j) {
    const int t = tc * 64 + 2 * j + tpar;
    f32x4 a0 = {0.f, 0.f, 0.f, 0.f}, a1 = {0.f, 0.f, 0.f, 0.f};
    const float* ap = x + ((size_t)b * TSEQ + t) * DDIM + kb + kg * 8;
#pragma unroll
    for (int ks = 0; ks < 8; ++ks) {
      const bf16x8 a = cvt8(ap + ks * 32);  // identical convert path to R4 enc
      a0 = MFMA16(a, wA[ks], a0);
      a1 = MFMA16(a, wB[ks], a1);
    }
#pragma unroll
    for (int r = 0; r < 4; ++r) {
      gbuf[tpar][wave & 1][kg * 4 + r][c15] = a0[r];
      gbuf[tpar][wave & 1][kg * 4 + r][16 + c15] = a1[r];
    }
    __syncthreads();
    if (tid < 128) {
      const int ll = tid >> 6, r6 = tid & 63, rw = r6 >> 2, dp = r6 & 3;
      const int tt = tc * 64 + 2 * j + ll;
      const size_t base = ((size_t)tt * 256 + wg0) * 256 + rw * 16 + dp;
#pragma unroll
      for (int g = 0; g < 4; ++g) {
        const int e = g * 8 + 2 * dp;
        const float v0 = gbuf[ll][0][rw][e] + gbuf[ll][1][rw][e];
        const float v1 = gbuf[ll][0][rw][e + 1] + gbuf[ll][1][rw][e + 1];
        union { _Float16 h[2]; unsigned u; } pk;
        pk.h[0] = (_Float16)v0; pk.h[1] = (_Float16)v1;
        __builtin_nontemporal_store(pk.u, &gx[base + g * 4]);  // write-once stream
      }
    }
    __syncthreads();
  }
}

// ---------------- encoder: diagonal wavefront; GX=1 reads precomputed x-half ----------------
template <int GX>
__global__ __launch_bounds__(256, 1) void enc_pass(
    const float* __restrict__ x,
    const float* __restrict__ Wih, const float* __restrict__ Whh,
    const float* __restrict__ bih, const float* __restrict__ bhh,
    bf16_t* __restrict__ hbuf, float* __restrict__ hT, float* __restrict__ cT,
    const unsigned* __restrict__ gx) {
  const int wg = blockIdx.x;
  const int grp = wg >> 6, slc = wg & 63;
  const int tid = threadIdx.x;
  const int wave = tid >> 6, lane = tid & 63;
  const int b0 = grp << 4, d0 = slc << 3;

  __shared__ float gbuf[2][4][16][33];
  __shared__ float bias_l[2][32];

  const int c15 = lane & 15, kg = lane >> 4;
  const int b = b0 + c15;

  bf16x8 wA[2][8], wB[2][8];
  load_weights(Wih, Whh, wave, c15, kg, d0, wA, wB);
  if (tid < 64) {
    const int l = tid >> 5, n = tid & 31;
    const int grow = (n >> 3) * DDIM + d0 + (n & 7);
    bias_l[l][n] = bih[l * 2048 + grow] + bhh[l * 2048 + grow];
  }
  if (tid < 128) {  // h0(-1)=0 -> slot1 (gen -1); h1(-1)=0 -> slot0 (gen 0); both tag=1
    const int l = tid >> 6, r6 = tid & 63, rw = r6 >> 2, dp = r6 & 3;
    const int slot = (l == 0) ? 1 : 0;
    stg_tag(&hbuf[((size_t)(l * 2 + slot) * NB + b0 + rw) * DDIM + d0 + 2 * dp],
            0.f, 0.f, 0x00010001u);
  }
  __syncthreads();

  float cA = 0.f, cB = 0.f;  // wave0: L0 c-state pair; wave1: L1 c-state pair

  for (int s = 0; s <= TSEQ; ++s) {
    const int p = s & 1, rp = p ^ 1;
    const unsigned patold = tagpat(s - 1);
    // -- pre-barrier: L0 x-half --
    f32x4 pa0 = {0.f, 0.f, 0.f, 0.f}, pa1 = {0.f, 0.f, 0.f, 0.f};
    unsigned gxr[4];
    if constexpr (GX) {
      if (tid < 64 && s < TSEQ) {  // 4 nt loads (read-once stream)
        const size_t base = ((size_t)s * 256 + wg) * 256 + (tid >> 2) * 16 + (tid & 3);
#pragma unroll
        for (int g = 0; g < 4; ++g) gxr[g] = __builtin_nontemporal_load(&gx[base + g * 4]);
      }
    } else {
      if (wave < 2 && s < TSEQ) {
        const int kq = wave << 8;
        const float* ap = x + ((size_t)b * TSEQ + s) * DDIM + kq + kg * 8;
#pragma unroll
        for (int ks = 0; ks < 8; ++ks) {
          const bf16x8 a = cvt8(ap + ks * 32);
          pa0 = MFMA16(a, wA[0][ks], pa0);
          pa1 = MFMA16(a, wB[0][ks], pa1);
        }
      }
    }
    __syncthreads();
    if (wave >= 2) {  // L0-recurrent (h0(s-1)) + L1-recurrent (h1(s-1)), tag-retry
      const int kq = (wave - 2) << 8;
      FRAG f0[8], f1[8];
      const bf16_t* a0p = hbuf + ((size_t)(0 * 2 + rp) * NB + b) * DDIM + kq + kg * 8;
      const bf16_t* a1p = hbuf + ((size_t)(1 * 2 + rp) * NB + b) * DDIM + kq + kg * 8;
      int guard = 0;
      for (;;) {
        if (s < TSEQ) {
#pragma unroll
          for (int ks = 0; ks < 8; ++ks) ldg_issue(a0p + ks * 32, f0[ks].i);
        }
        if (s >= 1) {
#pragma unroll
          for (int ks = 0; ks < 8; ++ks) ldg_issue(a1p + ks * 32, f1[ks].i);
        }
        vm_wait0();
        unsigned bad = 0;
        if (s < TSEQ) {
#pragma unroll
          for (int ks = 0; ks < 8; ++ks) bad |= chk4(f0[ks].i, patold);
        }
        if (s >= 1) {
#pragma unroll
          for (int ks = 0; ks < 8; ++ks) bad |= chk4(f1[ks].i, patold);
        }
        if (__all(bad == 0) || ++guard > RETRY_CAP) break;
      }
      if (s < TSEQ) {
        f32x4 a0 = {0.f, 0.f, 0.f, 0.f}, a1 = {0.f, 0.f, 0.f, 0.f};
#pragma unroll
        for (int ks = 0; ks < 8; ++ks) {
          a0 = MFMA16(f0[ks].v, wA[0][ks], a0);
          a1 = MFMA16(f0[ks].v, wB[0][ks], a1);
        }
#pragma unroll
        for (int r = 0; r < 4; ++r) {
          gbuf[0][wave][kg * 4 + r][c15] = a0[r];
          gbuf[0][wave][kg * 4 + r][16 + c15] = a1[r];
        }
      }
      if (s >= 1) {
        f32x4 a0 = {0.f, 0.f, 0.f, 0.f}, a1 = {0.f, 0.f, 0.f, 0.f};
#pragma unroll
        for (int ks = 0; ks < 8; ++ks) {
          a0 = MFMA16(f1[ks].v, wA[1][ks], a0);
          a1 = MFMA16(f1[ks].v, wB[1][ks], a1);
        }
#pragma unroll
        for (int r = 0; r < 4; ++r) {
          gbuf[1][wave][kg * 4 + r][c15] = a0[r];
          gbuf[1][wave][kg * 4 + r][16 + c15] = a1[r];
        }
      }
    } else {
      if constexpr (!GX) {
        if (s < TSEQ) {  // commit x-half accumulators (post-barrier: race-safe)
#pragma unroll
          for (int r = 0; r < 4; ++r) {
            gbuf[0][wave][kg * 4 + r][c15] = pa0[r];
            gbuf[0][wave][kg * 4 + r][16 + c15] = pa1[r];
          }
        }
      }
      if (s >= 1) {  // L1 input half: A = h0(s-1), tag-retry
        const int kq = wave << 8;
        FRAG f[8];
        const bf16_t* ap = hbuf + ((size_t)(0 * 2 + rp) * NB + b) * DDIM + kq + kg * 8;
        int guard = 0;
        for (;;) {
#pragma unroll
          for (int ks = 0; ks < 8; ++ks) ldg_issue(ap + ks * 32, f[ks].i);
          vm_wait0();
          unsigned bad = 0;
#pragma unroll
          for (int ks = 0; ks < 8; ++ks) bad |= chk4(f[ks].i, patold);
          if (__all(bad == 0) || ++guard > RETRY_CAP) break;
        }
        f32x4 a0 = {0.f, 0.f, 0.f, 0.f}, a1 = {0.f, 0.f, 0.f, 0.f};
#pragma unroll
        for (int ks = 0; ks < 8; ++ks) {
          a0 = MFMA16(f[ks].v, wA[1][ks], a0);
          a1 = MFMA16(f[ks].v, wB[1][ks], a1);
        }
#pragma unroll
        for (int r = 0; r < 4; ++r) {
          gbuf[1][wave][kg * 4 + r][c15] = a0[r];
          gbuf[1][wave][kg * 4 + r][16 + c15] = a1[r];
        }
      }
    }
    __syncthreads();
    // -- epilogue: wave0 -> L0, wave1 -> L1; stores carry tag(s) --
    if (tid < 128) {
      const int ll = tid >> 6, r6 = tid & 63, rw = r6 >> 2, dp = r6 & 3;
      const bool act = (ll == 0) ? (s < TSEQ) : (s >= 1);
      if (act) {
        const unsigned pat = tagpat(s);
        float gs[4][2];
#pragma unroll
        for (int g = 0; g < 4; ++g) {
          gs[g][0] = bias_l[ll][g * 8 + 2 * dp];
          gs[g][1] = bias_l[ll][g * 8 + 2 * dp + 1];
        }
        if (GX && ll == 0) {
#pragma unroll
          for (int g = 0; g < 4; ++g) {
            union { unsigned u; _Float16 h[2]; } dk;
            dk.u = gxr[g];
            gs[g][0] += (float)dk.h[0];
            gs[g][1] += (float)dk.h[1];
          }
        }
        const int q0 = (GX && ll == 0) ? 2 : 0;
#pragma unroll
        for (int q = 0; q < 4; ++q) {
          if (q >= q0) {
#pragma unroll
            for (int g = 0; g < 4; ++g) {
              const int e = g * 8 + 2 * dp;
              gs[g][0] += gbuf[ll][q][rw][e];
              gs[g][1] += gbuf[ll][q][rw][e + 1];
            }
          }
        }
        float hv2[2], cv2[2];
#pragma unroll
        for (int e2 = 0; e2 < 2; ++e2) {
          const float iv = sigm_f(gs[0][e2]), fv = sigm_f(gs[1][e2]);
          const float gv = tanh_f(gs[2][e2]), ov = sigm_f(gs[3][e2]);
          float& cs = (e2 == 0) ? cA : cB;
          cs = fv * cs + iv * gv;
          cv2[e2] = cs;
          hv2[e2] = ov * tanh_f(cs);
        }
        const int b2 = b0 + rw, dc = d0 + dp * 2;
        stg_tag(&hbuf[((size_t)(ll * 2 + p) * NB + b2) * DDIM + dc], hv2[0], hv2[1], pat);
        if ((ll == 0 && s == TSEQ - 1) || (ll == 1 && s == TSEQ)) {
          *(float2*)&hT[((size_t)ll * NB + b2) * DDIM + dc] = float2{hv2[0], hv2[1]};
          *(float2*)&cT[((size_t)ll * NB + b2) * DDIM + dc] = float2{cv2[0], cv2[1]};
        }
      }
    }
  }
}

// ---------------- decoder: serial chain, 1024 levels ----------------
__global__ __launch_bounds__(256, 1) void dec_pass(
    const float* __restrict__ initial,
    const float* __restrict__ Wih, const float* __restrict__ Whh,
    const float* __restrict__ bih, const float* __restrict__ bhh,
    const float* __restrict__ h_init, const float* __restrict__ c_init,
    bf16_t* __restrict__ hbuf, bf16_t* __restrict__ ybuf,
    float* __restrict__ out) {
  const int wg = blockIdx.x;
  const int grp = wg >> 6, slc = wg & 63;
  const int tid = threadIdx.x;
  const int wave = tid >> 6, lane = tid & 63;
  const int b0 = grp << 4, d0 = slc << 3;

  __shared__ float gbuf[4][16][33];
  __shared__ float bias_l[2][32];

  const int c15 = lane & 15, kg = lane >> 4;
  const int b = b0 + c15;

  bf16x8 wA[2][8], wB[2][8];
  load_weights(Wih, Whh, wave, c15, kg, d0, wA, wB);
  if (tid < 64) {
    const int l = tid >> 5, n = tid & 31;
    const int grow = (n >> 3) * DDIM + d0 + (n & 7);
    bias_l[l][n] = bih[l * 2048 + grow] + bhh[l * 2048 + grow];
  }
  if (tid < 128) {  // h_init -> slot1 (gen -1, tag 1)
    const int l = tid >> 6, r6 = tid & 63, rw = r6 >> 2, dp = r6 & 3;
    const int b2 = b0 + rw, dc = d0 + 2 * dp;
    const float2 hv = *(const float2*)&h_init[((size_t)l * NB + b2) * DDIM + dc];
    stg_tag(&hbuf[((size_t)(l * 2 + 1) * NB + b2) * DDIM + dc], hv.x, hv.y, 0x00010001u);
  }
  if (tid < 64) {  // y(-1)=initial -> slot1 (gen -1, tag 1)
    const int rw = tid >> 2, dp = tid & 3;
    const int dc = d0 + 2 * dp;
    stg_tag(&ybuf[((size_t)1 * NB + b0 + rw) * DDIM + dc], initial[dc], initial[dc + 1],
            0x00010001u);
  }
  const int rw0 = lane >> 2, dp0 = lane & 3;
  float cA0 = 0.f, cB0 = 0.f, cA1 = 0.f, cB1 = 0.f;
  if (wave == 0) {
    const float2 c0 = *(const float2*)&c_init[((size_t)0 * NB + b0 + rw0) * DDIM + d0 + 2 * dp0];
    const float2 c1 = *(const float2*)&c_init[((size_t)1 * NB + b0 + rw0) * DDIM + d0 + 2 * dp0];
    cA0 = c0.x; cB0 = c0.y; cA1 = c1.x; cB1 = c1.y;
  }
  __syncthreads();

  auto level = [&](auto lcc, const int t, const int p, const int rp) {
    constexpr int LC = decltype(lcc)::v;
    const unsigned patold = tagpat(t - 1);
    f32x4 pa0 = {0.f, 0.f, 0.f, 0.f}, pa1 = {0.f, 0.f, 0.f, 0.f};
    // -- pre-barrier: recurrent half h_LC(t-1) (tag-retry; covers init race) --
    if (wave >= 2) {
      const int kq = (wave - 2) << 8;
      FRAG f[8];
      const bf16_t* ap = hbuf + ((size_t)(LC * 2 + rp) * NB + b) * DDIM + kq + kg * 8;
      int guard = 0;
      for (;;) {
#pragma unroll
        for (int ks = 0; ks < 8; ++ks) ldg_issue(ap + ks * 32, f[ks].i);
        vm_wait0();
        unsigned bad = 0;
#pragma unroll
        for (int ks = 0; ks < 8; ++ks) bad |= chk4(f[ks].i, patold);
        if (__all(bad == 0) || ++guard > RETRY_CAP) break;
      }
#pragma unroll
      for (int ks = 0; ks < 8; ++ks) {
        pa0 = MFMA16(f[ks].v, wA[LC][ks], pa0);
        pa1 = MFMA16(f[ks].v, wB[LC][ks], pa1);
      }
    }
    __syncthreads();
    if (wave >= 2) {
#pragma unroll
      for (int r = 0; r < 4; ++r) {
        gbuf[wave][kg * 4 + r][c15] = pa0[r];
        gbuf[wave][kg * 4 + r][16 + c15] = pa1[r];
      }
    } else {  // fresh half: L0 reads y(t-1) [gen t-1]; L1 reads h0(t) [gen t]
      const int kq = wave << 8;
      const unsigned patf = (LC == 0) ? patold : tagpat(t);
      const bf16_t* base = (LC == 0) ? (ybuf + (size_t)rp * NB * DDIM)
                                     : (hbuf + (size_t)(0 * 2 + p) * NB * DDIM);
      const bf16_t* ap = base + (size_t)b * DDIM + kq + kg * 8;
      FRAG f[8];
      int guard = 0;
      for (;;) {
#pragma unroll
        for (int ks = 0; ks < 8; ++ks) ldg_issue(ap + ks * 32, f[ks].i);
        vm_wait0();
        unsigned bad = 0;
#pragma unroll
        for (int ks = 0; ks < 8; ++ks) bad |= chk4(f[ks].i, patf);
        if (__all(bad == 0) || ++guard > RETRY_CAP) break;
      }
      f32x4 a0 = {0.f, 0.f, 0.f, 0.f}, a1 = {0.f, 0.f, 0.f, 0.f};
#pragma unroll
      for (int ks = 0; ks < 8; ++ks) {
        a0 = MFMA16(f[ks].v, wA[LC][ks], a0);
        a1 = MFMA16(f[ks].v, wB[LC][ks], a1);
      }
#pragma unroll
      for (int r = 0; r < 4; ++r) {
        gbuf[wave][kg * 4 + r][c15] = a0[r];
        gbuf[wave][kg * 4 + r][16 + c15] = a1[r];
      }
    }
    __syncthreads();
    // -- epilogue (wave0): h/y stores carry tag(t) --
    if (tid < 64) {
      const unsigned pat = tagpat(t);
      float hv2[2];
#pragma unroll
      for (int e2 = 0; e2 < 2; ++e2) {
        const int e = dp0 * 2 + e2;
        float gi = bias_l[LC][e],      gf = bias_l[LC][8 + e];
        float gg = bias_l[LC][16 + e], go = bias_l[LC][24 + e];
#pragma unroll
        for (int q = 0; q < 4; ++q) {
          gi += gbuf[q][rw0][e];
          gf += gbuf[q][rw0][8 + e];
          gg += gbuf[q][rw0][16 + e];
          go += gbuf[q][rw0][24 + e];
        }
        const float iv = sigm_f(gi), fv = sigm_f(gf), gv = tanh_f(gg), ov = sigm_f(go);
        float& cs = (LC == 0) ? ((e2 == 0) ? cA0 : cB0) : ((e2 == 0) ? cA1 : cB1);
        cs = fv * cs + iv * gv;
        hv2[e2] = ov * tanh_f(cs);
      }
      const int b2 = b0 + rw0, dc = d0 + dp0 * 2;
      stg_tag(&hbuf[((size_t)(LC * 2 + p) * NB + b2) * DDIM + dc], hv2[0], hv2[1], pat);
      if (LC == 1) {
        stg_tag(&ybuf[((size_t)p * NB + b2) * DDIM + dc], hv2[0], hv2[1], pat);
        union { float f[2]; unsigned long long u; } ov;
        ov.f[0] = hv2[0]; ov.f[1] = hv2[1];  // nt: out is a write-once stream
        __builtin_nontemporal_store(ov.u, (unsigned long long*)&out[((size_t)b2 * TSEQ + t) * DDIM + dc]);
      }
    }
  };

  for (int t = 0; t < TSEQ; ++t) {
    const int p = t & 1, rp = p ^ 1;
    level(IC<0>{}, t, p, rp);
    level(IC<1>{}, t, p, rp);
  }
}

__global__ __launch_bounds__(512) void vae_kernel(
    const float* __restrict__ hT, const float* __restrict__ cT,
    const float* __restrict__ hmuW, const float* __restrict__ hmub,
    const float* __restrict__ hsigW, const float* __restrict__ hsigb,
    const float* __restrict__ houtW, const float* __restrict__ houtb,
    const float* __restrict__ cmuW, const float* __restrict__ cmub,
    const float* __restrict__ csigW, const float* __restrict__ csigb,
    const float* __restrict__ coutW, const float* __restrict__ coutb,
    const float* __restrict__ eps_h, const float* __restrict__ eps_c,
    float* __restrict__ h2, float* __restrict__ c2, float* __restrict__ out) {
  const int bid = blockIdx.x;  // (hc, layer, b)
  const int b = bid & 63;
  const int l = (bid >> 6) & 1;
  const int hc = bid >> 7;
  const int tid = threadIdx.x;

  const float* S    = (hc ? cT : hT) + (l * 64 + b) * 512;
  const float* muW  = (hc ? cmuW : hmuW) + l * 64 * 512;
  const float* mub  = (hc ? cmub : hmub) + l * 64;
  const float* sigW = (hc ? csigW : hsigW) + l * 64 * 512;
  const float* sigb = (hc ? csigb : hsigb) + l * 64;
  const float* outW = (hc ? coutW : houtW) + l * 512 * 64;
  const float* outb = (hc ? coutb : houtb) + l * 512;
  const float* eps  = (hc ? eps_c : eps_h) + (l * 64 + b) * 64;
  float* S2 = (hc ? c2 : h2) + (l * 64 + b) * 512;

  __shared__ float srow[512];
  __shared__ float z[64];
  srow[tid] = S[tid];
  __syncthreads();
  if (tid < 64) {
    const float* wm = muW + tid * 512;
    const float* ws = sigW + tid * 512;
    float mu = mub[tid], sg = sigb[tid];
    for (int d = 0; d < 512; ++d) {
      mu = fmaf(srow[d], wm[d], mu);
      sg = fmaf(srow[d], ws[d], sg);
    }
    z[tid] = mu + eps[tid] * sg;
    const size_t base = (size_t)64 * 512 * 512;
    const size_t idx = ((size_t)(hc * 2 + l) * 64 + b) * 64 + tid;
    out[base + idx] = mu;
    out[base + 4 * 64 * 64 + idx] = sg;
  }
  __syncthreads();
  {
    const float* wo = outW + tid * 64;
    float acc = outb[tid];
#pragma unroll 8
    for (int g = 0; g < 64; ++g) acc = fmaf(z[g], wo[g], acc);
    S2[tid] = acc;
  }
}

extern "C" void kernel_launch(void* const* d_in, const int* in_sizes, int n_in,
                              void* d_out, int out_size, void* d_ws, size_t ws_size,
                              hipStream_t stream) {
  const float* x       = (const float*)d_in[0];
  const float* initial = (const float*)d_in[1];
  const float* eWih    = (const float*)d_in[2];
  const float* eWhh    = (const float*)d_in[3];
  const float* ebih    = (const float*)d_in[4];
  const float* ebhh    = (const float*)d_in[5];
  const float* dWih    = (const float*)d_in[6];
  const float* dWhh    = (const float*)d_in[7];
  const float* dbih    = (const float*)d_in[8];
  const float* dbhh    = (const float*)d_in[9];
  const float* hmuW    = (const float*)d_in[10];
  const float* hmub    = (const float*)d_in[11];
  const float* hsigW   = (const float*)d_in[12];
  const float* hsigb   = (const float*)d_in[13];
  const float* houtW   = (const float*)d_in[14];
  const float* houtb   = (const float*)d_in[15];
  const float* cmuW    = (const float*)d_in[16];
  const float* cmub    = (const float*)d_in[17];
  const float* csigW   = (const float*)d_in[18];
  const float* csigb   = (const float*)d_in[19];
  const float* coutW   = (const float*)d_in[20];
  const float* coutb   = (const float*)d_in[21];
  const float* eps_h   = (const float*)d_in[22];
  const float* eps_c   = (const float*)d_in[23];

  char* ws = (char*)d_ws;
  bf16_t* enc_hbuf = (bf16_t*)(ws + OFF_ENC_HBUF);
  bf16_t* dec_hbuf = (bf16_t*)(ws + OFF_DEC_HBUF);
  bf16_t* dec_ybuf = (bf16_t*)(ws + OFF_DEC_YBUF);
  float* hT = (float*)(ws + OFF_HT);
  float* cT = (float*)(ws + OFF_CT);
  float* h2 = (float*)(ws + OFF_H2);
  float* c2 = (float*)(ws + OFF_C2);
  unsigned* gx = (unsigned*)(ws + OFF_GX);
  float* out = (float*)d_out;

  // zero all exchange buffers every call: tag LSB of unwritten data must be 0
  hipMemsetAsync(ws, 0, OFF_HT, stream);

  const bool use_gx = (ws_size >= OFF_GX + GX_BYTES);
  if (use_gx) {
    gx_pass<<<2048, 256, 0, stream>>>(x, eWih, gx);
    enc_pass<1><<<256, 256, 0, stream>>>(x, eWih, eWhh, ebih, ebhh, enc_hbuf, hT, cT, gx);
  } else {
    enc_pass<0><<<256, 256, 0, stream>>>(x, eWih, eWhh, ebih, ebhh, enc_hbuf, hT, cT, nullptr);
  }
  vae_kernel<<<256, 512, 0, stream>>>(hT, cT, hmuW, hmub, hsigW, hsigb, houtW, houtb,
                                      cmuW, cmub, csigW, csigb, coutW, coutb,
                                      eps_h, eps_c, h2, c2, out);
  dec_pass<<<256, 256, 0, stream>>>(initial, dWih, dWhh, dbih, dbhh,
                                    h2, c2, dec_hbuf, dec_ybuf, out);
}